// Round 8
// baseline (344.026 us; speedup 1.0000x reference)
//
#include <hip/hip_runtime.h>

// MHA: B=2, S=2048, D=1024, H=16, HD=64. fp32 in/out, bf16 MFMA internally.
// ws layout (64 MB): qb/kb/vb bf16 [4096,1024] @0/8/16MB; Wq/k/v/o^T bf16
// [1024,1024] @24/26/28/30MB; q(pre-scaled 0.125*log2e),k [B,H,S,HD] @32/40MB;
// v^T [B,H,HD,S] @48MB; bmw u32 mask-words [64][32][32][2][16] @56MB (8MB);
// ctx bf16 @16MB (aliases vb).
//
// R17: no-LDS flash. R13/R14 plateau diagnosis: the 2 waves/SIMD are
// barrier-locked into the same phase (both pack -> VALU serializes, both PV ->
// matrix pipe serializes; wall = sum of phases, not max). Barriers existed only
// for shared LDS K/V staging -- but every fragment is a contiguous aligned 16B
// per-lane global load (K tile 8KB + V tile 8KB, L1/L2-resident, shared by the
// 2 blocks/CU and 16 q-blocks/bh). Remove LDS + barriers entirely; waves
// free-run and de-phase. Pipeline: S(i+1) from prefetched kf -> issue K(i+2) ->
// pack(i) -> PV(i) -> issue V(i+1). Single kf/vf reg sets, sA/sB double.
// proj3/gemm_out/prep unchanged from R16.

using s8v = __attribute__((ext_vector_type(8))) short;   // 8 bf16 (4 VGPRs)
using f4v = __attribute__((ext_vector_type(4))) float;   // MFMA acc (16x16)
using f16v = __attribute__((ext_vector_type(16))) float; // MFMA acc (32x32)
typedef unsigned long long u64;

__device__ __forceinline__ unsigned short f2bf(float f) {
  union { float f; unsigned int u; } v; v.f = f;
  return (unsigned short)((v.u + 0x7fffu + ((v.u >> 16) & 1u)) >> 16);  // RNE
}

// pack two f32 -> two bf16 (truncation): lo | hi<<16
__device__ __forceinline__ unsigned pkbf(float lo, float hi2) {
  return __builtin_amdgcn_perm(__float_as_uint(hi2), __float_as_uint(lo), 0x07060302);
}

__device__ __forceinline__ void gll16(const void* g, void* l) {
  __builtin_amdgcn_global_load_lds(
      (const __attribute__((address_space(1))) unsigned int*)g,
      (__attribute__((address_space(3))) unsigned int*)l, 16, 0, 0);
}

// ---------- merged prep: f2b (QKV), wtrans (4 weights), packed mask words ----------
__global__ void prep_kernel(const float* __restrict__ Q, const float* __restrict__ K,
                            const float* __restrict__ V,
                            unsigned short* __restrict__ qb, unsigned short* __restrict__ kb,
                            unsigned short* __restrict__ vb,
                            const float* __restrict__ W0, const float* __restrict__ W1,
                            const float* __restrict__ W2, const float* __restrict__ W3,
                            unsigned short* __restrict__ T0, unsigned short* __restrict__ T1,
                            unsigned short* __restrict__ T2, unsigned short* __restrict__ T3,
                            const int* __restrict__ mask, unsigned* __restrict__ bmw) {
  __shared__ unsigned short t[64][72];
  const int bid = blockIdx.x, tid = threadIdx.x;
  if (bid < 12288) {
    int z = bid >> 12;
    int idx = (bid & 4095) * 256 + tid;
    const float* in = (z == 0) ? Q : (z == 1) ? K : V;
    unsigned short* out = (z == 0) ? qb : (z == 1) ? kb : vb;
    float4 v = ((const float4*)in)[idx];
    ushort4 o;
    o.x = f2bf(v.x); o.y = f2bf(v.y); o.z = f2bf(v.z); o.w = f2bf(v.w);
    ((ushort4*)out)[idx] = o;
  } else if (bid < 13312) {
    int b = bid - 12288;
    int z = b >> 8, rem = b & 255;
    int k0 = (rem >> 4) * 64, n0 = (rem & 15) * 64;
    const float* W = (z == 0) ? W0 : (z == 1) ? W1 : (z == 2) ? W2 : W3;
    unsigned short* Wt = (z == 0) ? T0 : (z == 1) ? T1 : (z == 2) ? T2 : T3;
    for (int p = 0; p < 4; ++p) {
      int idx = p * 256 + tid;
      int row = idx >> 4, c4 = idx & 15;
      float4 v = *(const float4*)&W[(size_t)(k0 + row) * 1024 + n0 + c4 * 4];
      t[row][c4 * 4 + 0] = f2bf(v.x);
      t[row][c4 * 4 + 1] = f2bf(v.y);
      t[row][c4 * 4 + 2] = f2bf(v.z);
      t[row][c4 * 4 + 3] = f2bf(v.w);
    }
    __syncthreads();
    for (int p = 0; p < 2; ++p) {
      int idx = p * 256 + tid;
      int j = idx >> 3, c8 = idx & 7;
      unsigned short tmp[8];
      for (int i = 0; i < 8; ++i) tmp[i] = t[c8 * 8 + i][j];
      uint4 o;
      o.x = tmp[0] | ((unsigned)tmp[1] << 16);
      o.y = tmp[2] | ((unsigned)tmp[3] << 16);
      o.z = tmp[4] | ((unsigned)tmp[5] << 16);
      o.w = tmp[6] | ((unsigned)tmp[7] << 16);
      *(uint4*)&Wt[(size_t)(n0 + j) * 1024 + k0 + c8 * 8] = o;
    }
  } else {
    int g = (bid - 13312) * 256 + tid;          // [0, 2^21)
    int widx = g & 15, hi = (g >> 4) & 1, l31 = (g >> 5) & 31;
    int it = (g >> 10) & 31, rowblk = g >> 15;
    int ni = widx >> 3, kcl = (widx >> 2) & 1, e = widx & 3;
    int kk = 64 * it + 32 * ni + 16 * kcl + 4 * hi + (e >> 1) * 8 + (e & 1) * 2;
    int qrow = rowblk * 32 + l31;
    const int* mrow = mask + (size_t)qrow * 2048 + kk;
    unsigned wd = (mrow[0] ? 0xFFFFu : 0u) | (mrow[1] ? 0xFFFF0000u : 0u);
    bmw[g] = wd;
  }
}

// ---------- fused QKV projection GEMM, 128x128 tile + LDS-coalesced epilogue ----------
// z=0: q*(0.125*log2e) -> [B,H,S,HD]; z=1: k -> [B,H,S,HD]; z=2: v -> v^T [B,H,HD,S]
__global__ __launch_bounds__(256) void proj3_kernel(
    const unsigned short* __restrict__ A0, const unsigned short* __restrict__ A1,
    const unsigned short* __restrict__ A2,
    const unsigned short* __restrict__ W0, const unsigned short* __restrict__ W1,
    const unsigned short* __restrict__ W2,
    const float* __restrict__ b0, const float* __restrict__ b1, const float* __restrict__ b2,
    unsigned short* __restrict__ oq, unsigned short* __restrict__ ok,
    unsigned short* __restrict__ ovt) {
  const int z = blockIdx.z;
  const unsigned short* A  = (z == 0) ? A0 : (z == 1) ? A1 : A2;
  const unsigned short* Wt = (z == 0) ? W0 : (z == 1) ? W1 : W2;
  const float* bias        = (z == 0) ? b0 : (z == 1) ? b1 : b2;

  __shared__ __align__(16) unsigned short As[128 * 32];
  __shared__ __align__(16) unsigned short Bs[128 * 32];
  __shared__ __align__(16) unsigned short Ls[128][136];  // epilogue staging (34.8 KB)

  const int tid = threadIdx.x;
  const int lane = tid & 63, w = tid >> 6, ln = lane & 15, quad = lane >> 4;
  const int wm = (w & 1) * 64, wn = (w >> 1) * 64;
  const int m0 = blockIdx.x * 128, n0 = blockIdx.y * 128;

  const int slr = lane >> 2;
  const int schunk = (lane & 3) ^ ((lane >> 3) & 3);
  const int cfrag = (quad ^ ((ln >> 1) & 3)) * 8;

  f4v zero = {0.f, 0.f, 0.f, 0.f};
  f4v acc[4][4];
  for (int mi = 0; mi < 4; ++mi)
    for (int ni = 0; ni < 4; ++ni) acc[mi][ni] = zero;

  for (int kt = 0; kt < 1024; kt += 32) {
    __syncthreads();
    gll16(&A[(size_t)(m0 + w * 32 + slr) * 1024 + kt + schunk * 8],       &As[(w * 32) * 32]);
    gll16(&A[(size_t)(m0 + w * 32 + 16 + slr) * 1024 + kt + schunk * 8],  &As[(w * 32 + 16) * 32]);
    gll16(&Wt[(size_t)(n0 + w * 32 + slr) * 1024 + kt + schunk * 8],      &Bs[(w * 32) * 32]);
    gll16(&Wt[(size_t)(n0 + w * 32 + 16 + slr) * 1024 + kt + schunk * 8], &Bs[(w * 32 + 16) * 32]);
    __syncthreads();
    s8v a[4], b[4];
    for (int mi = 0; mi < 4; ++mi) a[mi] = *(const s8v*)&As[(wm + mi * 16 + ln) * 32 + cfrag];
    for (int ni = 0; ni < 4; ++ni) b[ni] = *(const s8v*)&Bs[(wn + ni * 16 + ln) * 32 + cfrag];
    if (z < 2) {
      for (int mi = 0; mi < 4; ++mi)
        for (int ni = 0; ni < 4; ++ni)
          acc[mi][ni] = __builtin_amdgcn_mfma_f32_16x16x32_bf16(a[mi], b[ni], acc[mi][ni], 0, 0, 0);
    } else {
      for (int mi = 0; mi < 4; ++mi)
        for (int ni = 0; ni < 4; ++ni)
          acc[mi][ni] = __builtin_amdgcn_mfma_f32_16x16x32_bf16(b[ni], a[mi], acc[mi][ni], 0, 0, 0);
    }
  }

  // ---- epilogue: dump (bias/scale applied) to Ls, then coalesced 16B stores ----
  if (z < 2) {
    const float qscale = (z == 0) ? 0.18033688f : 1.0f;  // 0.125 * log2(e)
    for (int mi = 0; mi < 4; ++mi) {
      int row = wm + mi * 16 + quad * 4;
      for (int ni = 0; ni < 4; ++ni) {
        int col = wn + ni * 16 + ln;
        float bvv = bias[n0 + col];
        for (int r = 0; r < 4; ++r)
          Ls[row + r][col] = f2bf((acc[mi][ni][r] + bvv) * qscale);
      }
    }
  } else {
    // dump transposed: Ls[tile_col][tile_row] so the store phase is shared
    for (int ni = 0; ni < 4; ++ni) {
      for (int r = 0; r < 4; ++r) {
        int colw = wn + ni * 16 + quad * 4 + r;
        float bvv = bias[n0 + colw];
        for (int mi = 0; mi < 4; ++mi) {
          int rowg = wm + mi * 16 + ln;
          Ls[colw][rowg] = f2bf(acc[mi][ni][r] + bvv);
        }
      }
    }
  }
  __syncthreads();

  if (z < 2) {
    unsigned short* outp = (z == 0) ? oq : ok;
    for (int p = 0; p < 8; ++p) {
      int row = p * 16 + (tid >> 4);       // tile row 0..127 (= s index)
      int cg  = tid & 15;                  // 8-col group
      uint4 vv = *(const uint4*)&Ls[row][cg * 8];
      int rb = m0 + row, b_ = rb >> 11, s = rb & 2047;
      int colg = n0 + cg * 8, h = colg >> 6, hd = colg & 63;
      *(uint4*)&outp[(((size_t)(b_ * 16 + h)) * 2048 + s) * 64 + hd] = vv;
    }
  } else {
    for (int p = 0; p < 8; ++p) {
      int rr = p * 16 + (tid >> 4);        // Ls row = tile col (= hd index)
      int cg = tid & 15;                   // 8 consecutive s
      uint4 vv = *(const uint4*)&Ls[rr][cg * 8];
      int colw = n0 + rr, h = colw >> 6, hd = colw & 63;
      int sg = m0 + cg * 8, b_ = sg >> 11, ss = sg & 2047;
      *(uint4*)&ovt[(((size_t)(b_ * 16 + h)) * 64 + hd) * 2048 + ss] = vv;
    }
  }
}

// ---------- flash attention R17: no-LDS, no-barrier, per-lane global gathers ----------
#define FLASH_ITER(i, SIN0, SIN1, SOUT0, SOUT1)                                 \
  {                                                                             \
    uint4 nA, nB, nC, nD;                                                       \
    if ((i) < 31) {                                                             \
      const uint4* m4 = (const uint4*)(mwp + ((i) + 1) * 1024);                 \
      nA = m4[0]; nB = m4[1]; nC = m4[2]; nD = m4[3];                           \
    }                                                                           \
    /* S(i+1) from prefetched kf (K(i+1)); waits only on those loads */         \
    __builtin_amdgcn_s_setprio(1);                                              \
    if ((i) < 31) {                                                             \
      SOUT0 = __builtin_amdgcn_mfma_f32_32x32x16_bf16(kf0[0], qf[0], zf, 0, 0, 0); \
      SOUT1 = __builtin_amdgcn_mfma_f32_32x32x16_bf16(kf1[0], qf[0], zf, 0, 0, 0); \
      _Pragma("unroll")                                                         \
      for (int c = 1; c < 4; ++c) {                                             \
        SOUT0 = __builtin_amdgcn_mfma_f32_32x32x16_bf16(kf0[c], qf[c], SOUT0, 0, 0, 0); \
        SOUT1 = __builtin_amdgcn_mfma_f32_32x32x16_bf16(kf1[c], qf[c], SOUT1, 0, 0, 0); \
      }                                                                         \
    }                                                                           \
    __builtin_amdgcn_s_setprio(0);                                              \
    if ((i) < 30) LK((i) + 2);    /* reissue into kf; cover = pack+PV+next-S */ \
    /* pack(i): p = 2^s * maskbit -> bf16 pairs -> permlane -> PV A-frags */    \
    s8v pf[4];                                                                  \
    _Pragma("unroll")                                                           \
    for (int ni = 0; ni < 2; ++ni) {                                            \
      const f16v sv = ni ? SIN1 : SIN0;                                         \
      _Pragma("unroll")                                                         \
      for (int kcl = 0; kcl < 2; ++kcl) {                                       \
        const int rb = 8 * kcl;                                                 \
        const uint4 mw = ni ? (kcl ? mwD : mwC) : (kcl ? mwB : mwA);            \
        unsigned x0 = pkbf(__builtin_amdgcn_exp2f(sv[rb + 0]),                  \
                           __builtin_amdgcn_exp2f(sv[rb + 1])) & mw.x;          \
        unsigned x1 = pkbf(__builtin_amdgcn_exp2f(sv[rb + 2]),                  \
                           __builtin_amdgcn_exp2f(sv[rb + 3])) & mw.y;          \
        unsigned y0 = pkbf(__builtin_amdgcn_exp2f(sv[rb + 4]),                  \
                           __builtin_amdgcn_exp2f(sv[rb + 5])) & mw.z;          \
        unsigned y1 = pkbf(__builtin_amdgcn_exp2f(sv[rb + 6]),                  \
                           __builtin_amdgcn_exp2f(sv[rb + 7])) & mw.w;          \
        asm("v_permlane32_swap_b32 %0, %1" : "+v"(x0), "+v"(y0));               \
        asm("v_permlane32_swap_b32 %0, %1" : "+v"(x1), "+v"(y1));               \
        union { uint4 u; s8v v; } cv;                                           \
        cv.u = make_uint4(x0, x1, y0, y1);                                      \
        pf[ni * 2 + kcl] = cv.v;                                                \
      }                                                                         \
    }                                                                           \
    /* PV(i): l += P@ones, O += P@V(i) (waits vf loads from last iter) */       \
    __builtin_amdgcn_s_setprio(1);                                              \
    _Pragma("unroll")                                                           \
    for (int kc = 0; kc < 4; ++kc)                                              \
      lac = __builtin_amdgcn_mfma_f32_32x32x16_bf16(pf[kc], ones, lac, 0, 0, 0);\
    _Pragma("unroll")                                                           \
    for (int kc = 0; kc < 4; ++kc) {                                            \
      o0 = __builtin_amdgcn_mfma_f32_32x32x16_bf16(pf[kc], vf0[kc], o0, 0, 0, 0); \
      o1 = __builtin_amdgcn_mfma_f32_32x32x16_bf16(pf[kc], vf1[kc], o1, 0, 0, 0); \
    }                                                                           \
    __builtin_amdgcn_s_setprio(0);                                              \
    if ((i) < 31) LV((i) + 1);    /* reissue into vf; cover = next-iter S+pack */ \
    mwA = nA; mwB = nB; mwC = nC; mwD = nD;                                     \
  }

__global__ __launch_bounds__(256, 2) void flash_kernel(
    const unsigned short* __restrict__ q, const unsigned short* __restrict__ k,
    const unsigned short* __restrict__ vt, const unsigned* __restrict__ bmw,
    unsigned short* __restrict__ ctx) {
  const int tid = threadIdx.x;
  const int lane = tid & 63, w = tid >> 6;
  const int l31 = lane & 31, hi = lane >> 5;
  const int q0 = blockIdx.x * 128;
  const int bh = blockIdx.y;
  const unsigned short* qg  = q  + ((size_t)bh * 2048 + q0) * 64;
  const unsigned short* kgb = k  + (size_t)bh * 2048 * 64;
  const unsigned short* vgb = vt + (size_t)bh * 64 * 2048;
  // mask-word base for this lane: bmw[rowblk][it][l31][hi][16]
  const unsigned* mwp = bmw + (size_t)(blockIdx.x * 4 + w) * 32768 + l31 * 32 + hi * 16;

  // Q fragments: wave w owns q-rows [w*32, w*32+32)
  const int qrow = w * 32 + l31;
  s8v qf[4];
#pragma unroll
  for (int c = 0; c < 4; ++c)
    qf[c] = *(const s8v*)&qg[(size_t)qrow * 64 + c * 16 + hi * 8];

  s8v ones;
#pragma unroll
  for (int i = 0; i < 8; ++i) ones[i] = (short)0x3F80;
  f16v zf;
#pragma unroll
  for (int i = 0; i < 16; ++i) zf[i] = 0.f;

  // per-lane gather bases (each frag is one contiguous aligned 16B load)
  const unsigned short* kp0 = kgb + (size_t)l31 * 64 + hi * 8;        // + it*4096 + c*16
  const unsigned short* kp1 = kgb + (size_t)(32 + l31) * 64 + hi * 8;
  const unsigned short* vp0 = vgb + (size_t)l31 * 2048 + hi * 8;      // + it*64 + kc*16
  const unsigned short* vp1 = vgb + (size_t)(32 + l31) * 2048 + hi * 8;

  s8v kf0[4], kf1[4], vf0[4], vf1[4];
  auto LK = [&](int it) {
    const size_t off = (size_t)it * 4096;
#pragma unroll
    for (int c = 0; c < 4; ++c) {
      kf0[c] = *(const s8v*)&kp0[off + c * 16];
      kf1[c] = *(const s8v*)&kp1[off + c * 16];
    }
  };
  auto LV = [&](int it) {
    const int off = it * 64;
#pragma unroll
    for (int c = 0; c < 4; ++c) {
      vf0[c] = *(const s8v*)&vp0[off + c * 16];
      vf1[c] = *(const s8v*)&vp1[off + c * 16];
    }
  };

  // prologue: K(0) -> S(0); then K(1), V(0), mask(0) in flight
  LK(0);
  f16v sA0, sA1, sB0, sB1;
  sA0 = __builtin_amdgcn_mfma_f32_32x32x16_bf16(kf0[0], qf[0], zf, 0, 0, 0);
  sA1 = __builtin_amdgcn_mfma_f32_32x32x16_bf16(kf1[0], qf[0], zf, 0, 0, 0);
#pragma unroll
  for (int c = 1; c < 4; ++c) {
    sA0 = __builtin_amdgcn_mfma_f32_32x32x16_bf16(kf0[c], qf[c], sA0, 0, 0, 0);
    sA1 = __builtin_amdgcn_mfma_f32_32x32x16_bf16(kf1[c], qf[c], sA1, 0, 0, 0);
  }
  LK(1);
  LV(0);

  uint4 mwA, mwB, mwC, mwD;
  {
    const uint4* m4 = (const uint4*)mwp;
    mwA = m4[0]; mwB = m4[1]; mwC = m4[2]; mwD = m4[3];
  }

  f16v o0, o1, lac;
#pragma unroll
  for (int i = 0; i < 16; ++i) { o0[i] = 0.f; o1[i] = 0.f; lac[i] = 0.f; }

  for (int ii = 0; ii < 16; ++ii) {
    const int i0 = ii * 2;
    FLASH_ITER(i0,     sA0, sA1, sB0, sB1);
    FLASH_ITER(i0 + 1, sB0, sB1, sA0, sA1);
  }

  // O row r -> q_local=(r&3)+8*(r>>2)+4*hi, col=lane&31 (+32 for o1)
  const int b_ = bh >> 4, h = bh & 15;
#pragma unroll
  for (int r = 0; r < 16; ++r) {
    const int ql = (r & 3) + 8 * (r >> 2) + 4 * hi;
    const float inv = 1.f / lac[r];
    const int srw = q0 + w * 32 + ql;
    const size_t base = ((size_t)b_ * 2048 + srw) * 1024 + h * 64;
    ctx[base + l31] = f2bf(o0[r] * inv);
    ctx[base + 32 + l31] = f2bf(o1[r] * inv);
  }
}

// ---------- output projection, 128x128 tile (R15) ----------
__global__ __launch_bounds__(256) void gemm_out_kernel(
    const unsigned short* __restrict__ A, const unsigned short* __restrict__ Wt,
    const float* __restrict__ bias, float* __restrict__ out) {
  __shared__ __align__(16) unsigned short As[128 * 32];
  __shared__ __align__(16) unsigned short Bs[128 * 32];

  const int tid = threadIdx.x;
  const int lane = tid & 63, w = tid >> 6, ln = lane & 15, quad = lane >> 4;
  const int wm = (w & 1) * 64, wn = (w >> 1) * 64;
  const int m0 = blockIdx.x * 128, n0 = blockIdx.y * 128;

  const int slr = lane >> 2;
  const int schunk = (lane & 3) ^ ((lane >> 3) & 3);
  const int cfrag = (quad ^ ((ln >> 1) & 3)) * 8;

  f4v zero = {0.f, 0.f, 0.f, 0.f};
  f4v acc[4][4];
  for (int mi = 0; mi < 4; ++mi)
    for (int ni = 0; ni < 4; ++ni) acc[mi][ni] = zero;

  for (int kt = 0; kt < 1024; kt += 32) {
    __syncthreads();
    gll16(&A[(size_t)(m0 + w * 32 + slr) * 1024 + kt + schunk * 8],       &As[(w * 32) * 32]);
    gll16(&A[(size_t)(m0 + w * 32 + 16 + slr) * 1024 + kt + schunk * 8],  &As[(w * 32 + 16) * 32]);
    gll16(&Wt[(size_t)(n0 + w * 32 + slr) * 1024 + kt + schunk * 8],      &Bs[(w * 32) * 32]);
    gll16(&Wt[(size_t)(n0 + w * 32 + 16 + slr) * 1024 + kt + schunk * 8], &Bs[(w * 32 + 16) * 32]);
    __syncthreads();
    s8v a[4], b[4];
    for (int mi = 0; mi < 4; ++mi) a[mi] = *(const s8v*)&As[(wm + mi * 16 + ln) * 32 + cfrag];
    for (int ni = 0; ni < 4; ++ni) b[ni] = *(const s8v*)&Bs[(wn + ni * 16 + ln) * 32 + cfrag];
    for (int mi = 0; mi < 4; ++mi)
      for (int ni = 0; ni < 4; ++ni)
        acc[mi][ni] = __builtin_amdgcn_mfma_f32_16x16x32_bf16(a[mi], b[ni], acc[mi][ni], 0, 0, 0);
  }

  for (int mi = 0; mi < 4; ++mi) {
    int rb = m0 + wm + mi * 16 + quad * 4;
    for (int ni = 0; ni < 4; ++ni) {
      int col = n0 + wn + ni * 16 + ln;
      float bvv = bias[col];
      for (int r = 0; r < 4; ++r)
        out[(size_t)(rb + r) * 1024 + col] = acc[mi][ni][r] + bvv;
    }
  }
}

extern "C" void kernel_launch(void* const* d_in, const int* in_sizes, int n_in,
                              void* d_out, int out_size, void* d_ws, size_t ws_size,
                              hipStream_t stream) {
  const float* Q  = (const float*)d_in[0];
  const float* K  = (const float*)d_in[1];
  const float* V  = (const float*)d_in[2];
  const int* mask = (const int*)d_in[3];
  const float* Wq = (const float*)d_in[4];
  const float* bq = (const float*)d_in[5];
  const float* Wk = (const float*)d_in[6];
  const float* bk = (const float*)d_in[7];
  const float* Wv = (const float*)d_in[8];
  const float* bv = (const float*)d_in[9];
  const float* Wo = (const float*)d_in[10];
  const float* bo = (const float*)d_in[11];
  float* out = (float*)d_out;

  char* ws = (char*)d_ws;
  const size_t MB = 1u << 20;
  unsigned short* qb  = (unsigned short*)(ws + 0 * MB);
  unsigned short* kb  = (unsigned short*)(ws + 8 * MB);
  unsigned short* vb  = (unsigned short*)(ws + 16 * MB);
  unsigned short* wqt = (unsigned short*)(ws + 24 * MB);
  unsigned short* wkt = (unsigned short*)(ws + 26 * MB);
  unsigned short* wvt = (unsigned short*)(ws + 28 * MB);
  unsigned short* wot = (unsigned short*)(ws + 30 * MB);
  unsigned short* qh  = (unsigned short*)(ws + 32 * MB);
  unsigned short* kh  = (unsigned short*)(ws + 40 * MB);
  unsigned short* vth = (unsigned short*)(ws + 48 * MB);
  unsigned* bmw       = (unsigned*)(ws + 56 * MB);       // 8 MB of packed mask words
  unsigned short* ctx = (unsigned short*)(ws + 16 * MB);  // aliases vb (dead after proj3)

  prep_kernel<<<21504, 256, 0, stream>>>(Q, K, V, qb, kb, vb,
                                         Wq, Wk, Wv, Wo, wqt, wkt, wvt, wot,
                                         mask, bmw);
  proj3_kernel<<<dim3(32, 8, 3), 256, 0, stream>>>(qb, kb, vb, wqt, wkt, wvt,
                                                   bq, bk, bv, qh, kh, vth);
  flash_kernel<<<dim3(16, 32), 256, 0, stream>>>(qh, kh, vth, bmw, ctx);
  gemm_out_kernel<<<dim3(32, 8), 256, 0, stream>>>(ctx, wot, bo, out);
}

// Round 9
// 272.271 us; speedup vs baseline: 1.2635x; 1.2635x over previous
//
#include <hip/hip_runtime.h>

// MHA: B=2, S=2048, D=1024, H=16, HD=64. fp32 in/out, bf16 MFMA internally.
// ws layout (64 MB): Wq/k/v/o^T bf16 [1024,1024] @24/26/28/30MB; q(pre-scaled
// 0.125*log2e),k [B,H,S,HD] @32/40MB; v^T [B,H,HD,S] @48MB; bmw u32 mask-words
// [64][32][32][2][16] @56MB (8MB); ctx bf16 @16MB.
//
// R18: pipeline restructure. R17's no-LDS flash destroyed coalescing (per-lane
// 128B-stride gathers; 153us) -> flash reverted to R13 (best, 53us). The
// non-flash ~190us resisted K-loop (R15) and epilogue (R16) changes, so R18
// removes whole passes: (1) prep's QKV f2bf pass deleted -- proj3 reads fp32
// directly, converts via v_cvt_pk_bf16_f32 (RNE) during reg-staged A staging
// (saves 48MB fp32 read + 24MB write + 24MB re-read); (2) mask-packing moved
// into proj3's grid (z==3 slice, runs concurrent with GEMM blocks); (3) prep
// = weight-transpose only (1024 blocks).

using s8v = __attribute__((ext_vector_type(8))) short;   // 8 bf16 (4 VGPRs)
using f4v = __attribute__((ext_vector_type(4))) float;   // MFMA acc (16x16)
using f16v = __attribute__((ext_vector_type(16))) float; // MFMA acc (32x32)
typedef unsigned long long u64;

__device__ __forceinline__ unsigned short f2bf(float f) {
  union { float f; unsigned int u; } v; v.f = f;
  return (unsigned short)((v.u + 0x7fffu + ((v.u >> 16) & 1u)) >> 16);  // RNE
}

// pack two f32 -> two bf16 words, RNE (hardware cvt)
__device__ __forceinline__ unsigned cvtpk(float a, float b) {
  unsigned r;
  asm("v_cvt_pk_bf16_f32 %0, %1, %2" : "=v"(r) : "v"(a), "v"(b));
  return r;
}

// pack two f32 -> two bf16 (truncation): lo | hi<<16 (softmax probs only)
__device__ __forceinline__ unsigned pkbf(float lo, float hi2) {
  return __builtin_amdgcn_perm(__float_as_uint(hi2), __float_as_uint(lo), 0x07060302);
}

__device__ __forceinline__ void gll16(const void* g, void* l) {
  __builtin_amdgcn_global_load_lds(
      (const __attribute__((address_space(1))) unsigned int*)g,
      (__attribute__((address_space(3))) unsigned int*)l, 16, 0, 0);
}

// ---------- prep: weight transpose only (4 weights, 256 blocks each) ----------
__global__ void prep_kernel(const float* __restrict__ W0, const float* __restrict__ W1,
                            const float* __restrict__ W2, const float* __restrict__ W3,
                            unsigned short* __restrict__ T0, unsigned short* __restrict__ T1,
                            unsigned short* __restrict__ T2, unsigned short* __restrict__ T3) {
  __shared__ unsigned short t[64][72];
  const int bid = blockIdx.x, tid = threadIdx.x;
  int z = bid >> 8, rem = bid & 255;
  int k0 = (rem >> 4) * 64, n0 = (rem & 15) * 64;
  const float* W = (z == 0) ? W0 : (z == 1) ? W1 : (z == 2) ? W2 : W3;
  unsigned short* Wt = (z == 0) ? T0 : (z == 1) ? T1 : (z == 2) ? T2 : T3;
  for (int p = 0; p < 4; ++p) {
    int idx = p * 256 + tid;
    int row = idx >> 4, c4 = idx & 15;
    float4 v = *(const float4*)&W[(size_t)(k0 + row) * 1024 + n0 + c4 * 4];
    t[row][c4 * 4 + 0] = f2bf(v.x);
    t[row][c4 * 4 + 1] = f2bf(v.y);
    t[row][c4 * 4 + 2] = f2bf(v.z);
    t[row][c4 * 4 + 3] = f2bf(v.w);
  }
  __syncthreads();
  for (int p = 0; p < 2; ++p) {
    int idx = p * 256 + tid;
    int j = idx >> 3, c8 = idx & 7;
    unsigned short tmp[8];
    for (int i = 0; i < 8; ++i) tmp[i] = t[c8 * 8 + i][j];
    uint4 o;
    o.x = tmp[0] | ((unsigned)tmp[1] << 16);
    o.y = tmp[2] | ((unsigned)tmp[3] << 16);
    o.z = tmp[4] | ((unsigned)tmp[5] << 16);
    o.w = tmp[6] | ((unsigned)tmp[7] << 16);
    *(uint4*)&Wt[(size_t)(n0 + j) * 1024 + k0 + c8 * 8] = o;
  }
}

// ---------- fused QKV projection GEMM (fp32 in, in-reg cvt) + mask-pack slice ----------
// z=0: q*(0.125*log2e) -> [B,H,S,HD]; z=1: k; z=2: v -> v^T [B,H,HD,S];
// z=3: mask -> bmw packed AND-words (256 blocks x 32 chunks, concurrent).
__global__ __launch_bounds__(256) void proj3_kernel(
    const float* __restrict__ A0, const float* __restrict__ A1,
    const float* __restrict__ A2,
    const unsigned short* __restrict__ W0, const unsigned short* __restrict__ W1,
    const unsigned short* __restrict__ W2,
    const float* __restrict__ b0, const float* __restrict__ b1, const float* __restrict__ b2,
    unsigned short* __restrict__ oq, unsigned short* __restrict__ ok,
    unsigned short* __restrict__ ovt,
    const int* __restrict__ mask, unsigned* __restrict__ bmw) {
  const int z = blockIdx.z;
  const int tid = threadIdx.x;

  if (z == 3) {
    // mask words: widx = ni*8+kcl*4+e; word = (m[k0]?0xFFFF:0)|(m[k0+1]?0xFFFF0000:0),
    // k0 = 64*it + 32*ni + 16*kcl + 4*hi + (e>>1)*8 + (e&1)*2, q = rowblk*32+l31.
    const int idx = blockIdx.y * 32 + blockIdx.x;   // 0..255
    for (int j = 0; j < 32; ++j) {
      int g = idx * 256 + tid + j * 65536;          // [0, 2^21)
      int widx = g & 15, hi = (g >> 4) & 1, l31 = (g >> 5) & 31;
      int it = (g >> 10) & 31, rowblk = g >> 15;
      int ni = widx >> 3, kcl = (widx >> 2) & 1, e = widx & 3;
      int kk = 64 * it + 32 * ni + 16 * kcl + 4 * hi + (e >> 1) * 8 + (e & 1) * 2;
      int qrow = rowblk * 32 + l31;
      const int* mrow = mask + (size_t)qrow * 2048 + kk;
      unsigned wd = (mrow[0] ? 0xFFFFu : 0u) | (mrow[1] ? 0xFFFF0000u : 0u);
      bmw[g] = wd;
    }
    return;
  }

  const float* A = (z == 0) ? A0 : (z == 1) ? A1 : A2;
  const unsigned short* Wt = (z == 0) ? W0 : (z == 1) ? W1 : W2;
  const float* bias        = (z == 0) ? b0 : (z == 1) ? b1 : b2;

  __shared__ __align__(16) unsigned short As[128 * 32];
  __shared__ __align__(16) unsigned short Bs[128 * 32];
  __shared__ __align__(16) unsigned short Ls[128][136];  // epilogue staging

  const int lane = tid & 63, w = tid >> 6, ln = lane & 15, quad = lane >> 4;
  const int wm = (w & 1) * 64, wn = (w >> 1) * 64;
  const int m0 = blockIdx.x * 128, n0 = blockIdx.y * 128;

  const int slr = lane >> 2;
  const int schunk = (lane & 3) ^ ((lane >> 3) & 3);
  const int cfrag = (quad ^ ((ln >> 1) & 3)) * 8;

  // A staging assignment: thread covers rows ar, ar+64, chunk ac.
  // LDS[row][c] = global chunk (c ^ ((row>>1)&3)); note ((ar+64)>>1)&3 == ((ar>>1)&3).
  const int ar = tid >> 2, ac = tid & 3;
  const int asw = (ar >> 1) & 3;
  const int acg = (ac ^ asw) * 8;   // global k-offset (floats) of this thread's chunk

  f4v zero = {0.f, 0.f, 0.f, 0.f};
  f4v acc[4][4];
  for (int mi = 0; mi < 4; ++mi)
    for (int ni = 0; ni < 4; ++ni) acc[mi][ni] = zero;

  for (int kt = 0; kt < 1024; kt += 32) {
    __syncthreads();
    // B: bf16 weights direct-to-LDS
    gll16(&Wt[(size_t)(n0 + w * 32 + slr) * 1024 + kt + schunk * 8],      &Bs[(w * 32) * 32]);
    gll16(&Wt[(size_t)(n0 + w * 32 + 16 + slr) * 1024 + kt + schunk * 8], &Bs[(w * 32 + 16) * 32]);
    // A: fp32 -> bf16 reg-staged (swizzle-compatible with cfrag reads)
    {
      const float* p0 = &A[(size_t)(m0 + ar) * 1024 + kt + acg];
      const float* p1 = &A[(size_t)(m0 + ar + 64) * 1024 + kt + acg];
      float4 f0a = *(const float4*)p0, f0b = *(const float4*)(p0 + 4);
      float4 f1a = *(const float4*)p1, f1b = *(const float4*)(p1 + 4);
      *(uint4*)&As[ar * 32 + ac * 8] =
          make_uint4(cvtpk(f0a.x, f0a.y), cvtpk(f0a.z, f0a.w),
                     cvtpk(f0b.x, f0b.y), cvtpk(f0b.z, f0b.w));
      *(uint4*)&As[(ar + 64) * 32 + ac * 8] =
          make_uint4(cvtpk(f1a.x, f1a.y), cvtpk(f1a.z, f1a.w),
                     cvtpk(f1b.x, f1b.y), cvtpk(f1b.z, f1b.w));
    }
    __syncthreads();
    s8v a[4], b[4];
    for (int mi = 0; mi < 4; ++mi) a[mi] = *(const s8v*)&As[(wm + mi * 16 + ln) * 32 + cfrag];
    for (int ni = 0; ni < 4; ++ni) b[ni] = *(const s8v*)&Bs[(wn + ni * 16 + ln) * 32 + cfrag];
    if (z < 2) {
      for (int mi = 0; mi < 4; ++mi)
        for (int ni = 0; ni < 4; ++ni)
          acc[mi][ni] = __builtin_amdgcn_mfma_f32_16x16x32_bf16(a[mi], b[ni], acc[mi][ni], 0, 0, 0);
    } else {
      for (int mi = 0; mi < 4; ++mi)
        for (int ni = 0; ni < 4; ++ni)
          acc[mi][ni] = __builtin_amdgcn_mfma_f32_16x16x32_bf16(b[ni], a[mi], acc[mi][ni], 0, 0, 0);
    }
  }

  // ---- epilogue: dump (bias/scale applied) to Ls, then coalesced 16B stores ----
  if (z < 2) {
    const float qscale = (z == 0) ? 0.18033688f : 1.0f;  // 0.125 * log2(e)
    for (int mi = 0; mi < 4; ++mi) {
      int row = wm + mi * 16 + quad * 4;
      for (int ni = 0; ni < 4; ++ni) {
        int col = wn + ni * 16 + ln;
        float bvv = bias[n0 + col];
        for (int r = 0; r < 4; ++r)
          Ls[row + r][col] = f2bf((acc[mi][ni][r] + bvv) * qscale);
      }
    }
  } else {
    for (int ni = 0; ni < 4; ++ni) {
      for (int r = 0; r < 4; ++r) {
        int colw = wn + ni * 16 + quad * 4 + r;
        float bvv = bias[n0 + colw];
        for (int mi = 0; mi < 4; ++mi) {
          int rowg = wm + mi * 16 + ln;
          Ls[colw][rowg] = f2bf(acc[mi][ni][r] + bvv);
        }
      }
    }
  }
  __syncthreads();

  if (z < 2) {
    unsigned short* outp = (z == 0) ? oq : ok;
    for (int p = 0; p < 8; ++p) {
      int row = p * 16 + (tid >> 4);
      int cg  = tid & 15;
      uint4 vv = *(const uint4*)&Ls[row][cg * 8];
      int rb = m0 + row, b_ = rb >> 11, s = rb & 2047;
      int colg = n0 + cg * 8, h = colg >> 6, hd = colg & 63;
      *(uint4*)&outp[(((size_t)(b_ * 16 + h)) * 2048 + s) * 64 + hd] = vv;
    }
  } else {
    for (int p = 0; p < 8; ++p) {
      int rr = p * 16 + (tid >> 4);
      int cg = tid & 15;
      uint4 vv = *(const uint4*)&Ls[rr][cg * 8];
      int colw = n0 + rr, h = colw >> 6, hd = colw & 63;
      int sg = m0 + cg * 8, b_ = sg >> 11, ss = sg & 2047;
      *(uint4*)&ovt[(((size_t)(b_ * 16 + h)) * 64 + hd) * 2048 + ss] = vv;
    }
  }
}

// ---------- flash attention R13 (best measured): 4 waves x 32 q-rows, pipelined ----------
#define FLASH_ITER(i, SIN0, SIN1, SOUT0, SOUT1)                                 \
  {                                                                             \
    const int cur = (i) & 1;                                                    \
    uint4 nA, nB, nC, nD;                                                       \
    if ((i) < 31) {                                                             \
      const uint4* m4 = (const uint4*)(mwp + ((i) + 1) * 1024);                 \
      nA = m4[0]; nB = m4[1]; nC = m4[2]; nD = m4[3];                           \
    }                                                                           \
    /* S(i+1): issue first so the matrix pipe runs under pack(i)'s VALU */      \
    __builtin_amdgcn_s_setprio(1);                                              \
    if ((i) < 31) {                                                             \
      s8v ak0 = *(const s8v*)&k_s[cur ^ 1][l31][hi * 8];                        \
      s8v ak1 = *(const s8v*)&k_s[cur ^ 1][32 + l31][hi * 8];                   \
      SOUT0 = __builtin_amdgcn_mfma_f32_32x32x16_bf16(ak0, qf[0], zf, 0, 0, 0); \
      SOUT1 = __builtin_amdgcn_mfma_f32_32x32x16_bf16(ak1, qf[0], zf, 0, 0, 0); \
      _Pragma("unroll")                                                         \
      for (int c = 1; c < 4; ++c) {                                             \
        ak0 = *(const s8v*)&k_s[cur ^ 1][l31][c * 16 + hi * 8];                 \
        ak1 = *(const s8v*)&k_s[cur ^ 1][32 + l31][c * 16 + hi * 8];            \
        SOUT0 = __builtin_amdgcn_mfma_f32_32x32x16_bf16(ak0, qf[c], SOUT0, 0, 0, 0); \
        SOUT1 = __builtin_amdgcn_mfma_f32_32x32x16_bf16(ak1, qf[c], SOUT1, 0, 0, 0); \
      }                                                                         \
    }                                                                           \
    __builtin_amdgcn_s_setprio(0);                                              \
    /* pack(i): p = 2^s * maskbit, to bf16 pairs, permlane -> PV A-frags */     \
    s8v pf[4];                                                                  \
    _Pragma("unroll")                                                           \
    for (int ni = 0; ni < 2; ++ni) {                                            \
      const f16v sv = ni ? SIN1 : SIN0;                                         \
      _Pragma("unroll")                                                         \
      for (int kcl = 0; kcl < 2; ++kcl) {                                       \
        const int rb = 8 * kcl;                                                 \
        const uint4 mw = ni ? (kcl ? mwD : mwC) : (kcl ? mwB : mwA);            \
        unsigned x0 = pkbf(__builtin_amdgcn_exp2f(sv[rb + 0]),                  \
                           __builtin_amdgcn_exp2f(sv[rb + 1])) & mw.x;          \
        unsigned x1 = pkbf(__builtin_amdgcn_exp2f(sv[rb + 2]),                  \
                           __builtin_amdgcn_exp2f(sv[rb + 3])) & mw.y;          \
        unsigned y0 = pkbf(__builtin_amdgcn_exp2f(sv[rb + 4]),                  \
                           __builtin_amdgcn_exp2f(sv[rb + 5])) & mw.z;          \
        unsigned y1 = pkbf(__builtin_amdgcn_exp2f(sv[rb + 6]),                  \
                           __builtin_amdgcn_exp2f(sv[rb + 7])) & mw.w;          \
        asm("v_permlane32_swap_b32 %0, %1" : "+v"(x0), "+v"(y0));               \
        asm("v_permlane32_swap_b32 %0, %1" : "+v"(x1), "+v"(y1));               \
        union { uint4 u; s8v v; } cv;                                           \
        cv.u = make_uint4(x0, x1, y0, y1);                                      \
        pf[ni * 2 + kcl] = cv.v;                                                \
      }                                                                         \
    }                                                                           \
    /* PV(i): l += P@ones, O += P@V */                                          \
    __builtin_amdgcn_s_setprio(1);                                              \
    _Pragma("unroll")                                                           \
    for (int kc = 0; kc < 4; ++kc)                                              \
      lac = __builtin_amdgcn_mfma_f32_32x32x16_bf16(pf[kc], ones, lac, 0, 0, 0);\
    _Pragma("unroll")                                                           \
    for (int kc = 0; kc < 4; ++kc) {                                            \
      s8v bv0 = *(const s8v*)&v_s[cur][l31][kc * 16 + hi * 8];                  \
      s8v bv1 = *(const s8v*)&v_s[cur][32 + l31][kc * 16 + hi * 8];             \
      o0 = __builtin_amdgcn_mfma_f32_32x32x16_bf16(pf[kc], bv0, o0, 0, 0, 0);   \
      o1 = __builtin_amdgcn_mfma_f32_32x32x16_bf16(pf[kc], bv1, o1, 0, 0, 0);   \
    }                                                                           \
    __builtin_amdgcn_s_setprio(0);                                              \
    __syncthreads();                     /* A: V(i)/K(i+1) reads done */        \
    if ((i) < 30) WRITET(cur);           /* tile i+2 -> buf cur */              \
    if ((i) < 29) LOADT((i) + 3);                                               \
    __syncthreads();                     /* B: tile i+2 visible for iter i+1 */ \
    mwA = nA; mwB = nB; mwC = nC; mwD = nD;                                     \
  }

__global__ __launch_bounds__(256, 2) void flash_kernel(
    const unsigned short* __restrict__ q, const unsigned short* __restrict__ k,
    const unsigned short* __restrict__ vt, const unsigned* __restrict__ bmw,
    unsigned short* __restrict__ ctx) {
  __shared__ __align__(16) unsigned short k_s[2][64][72];
  __shared__ __align__(16) unsigned short v_s[2][64][72];

  const int tid = threadIdx.x;
  const int lane = tid & 63, w = tid >> 6;
  const int l31 = lane & 31, hi = lane >> 5;
  const int q0 = blockIdx.x * 128;
  const int bh = blockIdx.y;
  const unsigned short* qg  = q  + ((size_t)bh * 2048 + q0) * 64;
  const unsigned short* kgb = k  + (size_t)bh * 2048 * 64;
  const unsigned short* vgb = vt + (size_t)bh * 64 * 2048;
  // mask-word base for this lane: bmw[rowblk][it][l31][hi][16]
  const unsigned* mwp = bmw + (size_t)(blockIdx.x * 4 + w) * 32768 + l31 * 32 + hi * 16;

  // Q fragments direct from global: wave w owns q-rows [w*32, w*32+32)
  const int qrow = w * 32 + l31;
  s8v qf[4];
#pragma unroll
  for (int c = 0; c < 4; ++c)
    qf[c] = *(const s8v*)&qg[(size_t)qrow * 64 + c * 16 + hi * 8];

  s8v ones;
#pragma unroll
  for (int i = 0; i < 8; ++i) ones[i] = (short)0x3F80;
  f16v zf;
#pragma unroll
  for (int i = 0; i < 16; ++i) zf[i] = 0.f;

  // staging: 256 threads x 4 uint4 (one K tile + one V tile)
  const int srow = tid >> 3, sc8 = tid & 7;  // rows srow and srow+32

  uint4 kr0, kr1, vr0, vr1;
  auto LOADT = [&](int it) {
    const int kk = it * 64;
    kr0 = *(const uint4*)&kgb[(size_t)(kk + srow) * 64 + sc8 * 8];
    kr1 = *(const uint4*)&kgb[(size_t)(kk + srow + 32) * 64 + sc8 * 8];
    vr0 = *(const uint4*)&vgb[(size_t)srow * 2048 + kk + sc8 * 8];
    vr1 = *(const uint4*)&vgb[(size_t)(srow + 32) * 2048 + kk + sc8 * 8];
  };
  auto WRITET = [&](int b) {
    *(uint4*)&k_s[b][srow][sc8 * 8] = kr0;
    *(uint4*)&k_s[b][srow + 32][sc8 * 8] = kr1;
    *(uint4*)&v_s[b][srow][sc8 * 8] = vr0;
    *(uint4*)&v_s[b][srow + 32][sc8 * 8] = vr1;
  };

  LOADT(0); WRITET(0);
  LOADT(1); WRITET(1);
  LOADT(2);
  __syncthreads();

  // mask words for tile 0
  uint4 mwA, mwB, mwC, mwD;
  {
    const uint4* m4 = (const uint4*)mwp;
    mwA = m4[0]; mwB = m4[1]; mwC = m4[2]; mwD = m4[3];
  }

  // S(0) from k_s[0]
  f16v sA0, sA1, sB0, sB1;
  {
    s8v ak0 = *(const s8v*)&k_s[0][l31][hi * 8];
    s8v ak1 = *(const s8v*)&k_s[0][32 + l31][hi * 8];
    sA0 = __builtin_amdgcn_mfma_f32_32x32x16_bf16(ak0, qf[0], zf, 0, 0, 0);
    sA1 = __builtin_amdgcn_mfma_f32_32x32x16_bf16(ak1, qf[0], zf, 0, 0, 0);
#pragma unroll
    for (int c = 1; c < 4; ++c) {
      ak0 = *(const s8v*)&k_s[0][l31][c * 16 + hi * 8];
      ak1 = *(const s8v*)&k_s[0][32 + l31][c * 16 + hi * 8];
      sA0 = __builtin_amdgcn_mfma_f32_32x32x16_bf16(ak0, qf[c], sA0, 0, 0, 0);
      sA1 = __builtin_amdgcn_mfma_f32_32x32x16_bf16(ak1, qf[c], sA1, 0, 0, 0);
    }
  }

  f16v o0, o1, lac;
#pragma unroll
  for (int i = 0; i < 16; ++i) { o0[i] = 0.f; o1[i] = 0.f; lac[i] = 0.f; }

  for (int ii = 0; ii < 16; ++ii) {
    const int i0 = ii * 2;
    FLASH_ITER(i0,     sA0, sA1, sB0, sB1);
    FLASH_ITER(i0 + 1, sB0, sB1, sA0, sA1);
  }

  // O row r -> q_local=(r&3)+8*(r>>2)+4*hi, col=lane&31 (+32 for o1)
  const int b_ = bh >> 4, h = bh & 15;
#pragma unroll
  for (int r = 0; r < 16; ++r) {
    const int ql = (r & 3) + 8 * (r >> 2) + 4 * hi;
    const float inv = 1.f / lac[r];
    const int srw = q0 + w * 32 + ql;
    const size_t base = ((size_t)b_ * 2048 + srw) * 1024 + h * 64;
    ctx[base + l31] = f2bf(o0[r] * inv);
    ctx[base + 32 + l31] = f2bf(o1[r] * inv);
  }
}

// ---------- output projection, 128x128 tile ----------
__global__ __launch_bounds__(256) void gemm_out_kernel(
    const unsigned short* __restrict__ A, const unsigned short* __restrict__ Wt,
    const float* __restrict__ bias, float* __restrict__ out) {
  __shared__ __align__(16) unsigned short As[128 * 32];
  __shared__ __align__(16) unsigned short Bs[128 * 32];

  const int tid = threadIdx.x;
  const int lane = tid & 63, w = tid >> 6, ln = lane & 15, quad = lane >> 4;
  const int wm = (w & 1) * 64, wn = (w >> 1) * 64;
  const int m0 = blockIdx.x * 128, n0 = blockIdx.y * 128;

  const int slr = lane >> 2;
  const int schunk = (lane & 3) ^ ((lane >> 3) & 3);
  const int cfrag = (quad ^ ((ln >> 1) & 3)) * 8;

  f4v zero = {0.f, 0.f, 0.f, 0.f};
  f4v acc[4][4];
  for (int mi = 0; mi < 4; ++mi)
    for (int ni = 0; ni < 4; ++ni) acc[mi][ni] = zero;

  for (int kt = 0; kt < 1024; kt += 32) {
    __syncthreads();
    gll16(&A[(size_t)(m0 + w * 32 + slr) * 1024 + kt + schunk * 8],       &As[(w * 32) * 32]);
    gll16(&A[(size_t)(m0 + w * 32 + 16 + slr) * 1024 + kt + schunk * 8],  &As[(w * 32 + 16) * 32]);
    gll16(&Wt[(size_t)(n0 + w * 32 + slr) * 1024 + kt + schunk * 8],      &Bs[(w * 32) * 32]);
    gll16(&Wt[(size_t)(n0 + w * 32 + 16 + slr) * 1024 + kt + schunk * 8], &Bs[(w * 32 + 16) * 32]);
    __syncthreads();
    s8v a[4], b[4];
    for (int mi = 0; mi < 4; ++mi) a[mi] = *(const s8v*)&As[(wm + mi * 16 + ln) * 32 + cfrag];
    for (int ni = 0; ni < 4; ++ni) b[ni] = *(const s8v*)&Bs[(wn + ni * 16 + ln) * 32 + cfrag];
    for (int mi = 0; mi < 4; ++mi)
      for (int ni = 0; ni < 4; ++ni)
        acc[mi][ni] = __builtin_amdgcn_mfma_f32_16x16x32_bf16(a[mi], b[ni], acc[mi][ni], 0, 0, 0);
  }

  for (int mi = 0; mi < 4; ++mi) {
    int rb = m0 + wm + mi * 16 + quad * 4;
    for (int ni = 0; ni < 4; ++ni) {
      int col = n0 + wn + ni * 16 + ln;
      float bvv = bias[col];
      for (int r = 0; r < 4; ++r)
        out[(size_t)(rb + r) * 1024 + col] = acc[mi][ni][r] + bvv;
    }
  }
}

extern "C" void kernel_launch(void* const* d_in, const int* in_sizes, int n_in,
                              void* d_out, int out_size, void* d_ws, size_t ws_size,
                              hipStream_t stream) {
  const float* Q  = (const float*)d_in[0];
  const float* K  = (const float*)d_in[1];
  const float* V  = (const float*)d_in[2];
  const int* mask = (const int*)d_in[3];
  const float* Wq = (const float*)d_in[4];
  const float* bq = (const float*)d_in[5];
  const float* Wk = (const float*)d_in[6];
  const float* bk = (const float*)d_in[7];
  const float* Wv = (const float*)d_in[8];
  const float* bv = (const float*)d_in[9];
  const float* Wo = (const float*)d_in[10];
  const float* bo = (const float*)d_in[11];
  float* out = (float*)d_out;

  char* ws = (char*)d_ws;
  const size_t MB = 1u << 20;
  unsigned short* wqt = (unsigned short*)(ws + 24 * MB);
  unsigned short* wkt = (unsigned short*)(ws + 26 * MB);
  unsigned short* wvt = (unsigned short*)(ws + 28 * MB);
  unsigned short* wot = (unsigned short*)(ws + 30 * MB);
  unsigned short* qh  = (unsigned short*)(ws + 32 * MB);
  unsigned short* kh  = (unsigned short*)(ws + 40 * MB);
  unsigned short* vth = (unsigned short*)(ws + 48 * MB);
  unsigned* bmw       = (unsigned*)(ws + 56 * MB);        // 8 MB of packed mask words
  unsigned short* ctx = (unsigned short*)(ws + 16 * MB);  // flash output staging

  prep_kernel<<<1024, 256, 0, stream>>>(Wq, Wk, Wv, Wo, wqt, wkt, wvt, wot);
  proj3_kernel<<<dim3(32, 8, 4), 256, 0, stream>>>(Q, K, V, wqt, wkt, wvt,
                                                   bq, bk, bv, qh, kh, vth,
                                                   mask, bmw);
  flash_kernel<<<dim3(16, 32), 256, 0, stream>>>(qh, kh, vth, bmw, ctx);
  gemm_out_kernel<<<dim3(32, 8), 256, 0, stream>>>(ctx, wot, bo, out);
}

// Round 10
// 247.311 us; speedup vs baseline: 1.3911x; 1.1009x over previous
//
#include <hip/hip_runtime.h>

// MHA: B=2, S=2048, D=1024, H=16, HD=64. fp32 in/out, bf16 MFMA internally.
// ws layout (64 MB): qb/kb/vb bf16 [4096,1024] @0/8/16MB; Wq/k/v/o^T bf16
// [1024,1024] @24/26/28/30MB; q(pre-scaled 0.125*log2e),k [B,H,S,HD] @32/40MB;
// v^T [B,H,HD,S] @48MB; bmw u32 mask-words @56MB (8MB); ctx bf16 @16MB.
//
// R19: R18 exposed proj3 = 97us, MfmaUtil 10% -- latency-bound. Root cause:
// the K-loop's `barrier; gll16; barrier(vmcnt-drain); MFMA` shape gives the
// staging loads ZERO compute cover, exposing L2 latency all 32 steps, at only
// 3 blocks/CU (Ls pushed LDS to 51KB). Fix: (1) restore bf16-A gll16 path
// (R18's fp32 reg-staging cost +45us); (2) double-buffered LDS, ONE barrier
// per K-step -- STAGE(next) issues before frag-read+MFMA(cur), so loads get
// the full compute phase as cover; (3) Ls unioned with As/Bs (both dead when
// the other is live): proj3 LDS 51.2->34.8KB = 4 blocks/CU; gemm_out gets the
// same dbuf loop (32KB, 5 blocks/CU). Flash untouched (R13, 53us).

using s8v = __attribute__((ext_vector_type(8))) short;   // 8 bf16 (4 VGPRs)
using f4v = __attribute__((ext_vector_type(4))) float;   // MFMA acc (16x16)
using f16v = __attribute__((ext_vector_type(16))) float; // MFMA acc (32x32)
typedef unsigned long long u64;

__device__ __forceinline__ unsigned short f2bf(float f) {
  union { float f; unsigned int u; } v; v.f = f;
  return (unsigned short)((v.u + 0x7fffu + ((v.u >> 16) & 1u)) >> 16);  // RNE
}

// pack two f32 -> two bf16 (truncation): lo | hi<<16
__device__ __forceinline__ unsigned pkbf(float lo, float hi2) {
  return __builtin_amdgcn_perm(__float_as_uint(hi2), __float_as_uint(lo), 0x07060302);
}

__device__ __forceinline__ void gll16(const void* g, void* l) {
  __builtin_amdgcn_global_load_lds(
      (const __attribute__((address_space(1))) unsigned int*)g,
      (__attribute__((address_space(3))) unsigned int*)l, 16, 0, 0);
}

// ---------- merged prep: f2b (QKV), wtrans (4 weights), packed mask words ----------
__global__ void prep_kernel(const float* __restrict__ Q, const float* __restrict__ K,
                            const float* __restrict__ V,
                            unsigned short* __restrict__ qb, unsigned short* __restrict__ kb,
                            unsigned short* __restrict__ vb,
                            const float* __restrict__ W0, const float* __restrict__ W1,
                            const float* __restrict__ W2, const float* __restrict__ W3,
                            unsigned short* __restrict__ T0, unsigned short* __restrict__ T1,
                            unsigned short* __restrict__ T2, unsigned short* __restrict__ T3,
                            const int* __restrict__ mask, unsigned* __restrict__ bmw) {
  __shared__ unsigned short t[64][72];
  const int bid = blockIdx.x, tid = threadIdx.x;
  if (bid < 12288) {
    int z = bid >> 12;
    int idx = (bid & 4095) * 256 + tid;
    const float* in = (z == 0) ? Q : (z == 1) ? K : V;
    unsigned short* out = (z == 0) ? qb : (z == 1) ? kb : vb;
    float4 v = ((const float4*)in)[idx];
    ushort4 o;
    o.x = f2bf(v.x); o.y = f2bf(v.y); o.z = f2bf(v.z); o.w = f2bf(v.w);
    ((ushort4*)out)[idx] = o;
  } else if (bid < 13312) {
    int b = bid - 12288;
    int z = b >> 8, rem = b & 255;
    int k0 = (rem >> 4) * 64, n0 = (rem & 15) * 64;
    const float* W = (z == 0) ? W0 : (z == 1) ? W1 : (z == 2) ? W2 : W3;
    unsigned short* Wt = (z == 0) ? T0 : (z == 1) ? T1 : (z == 2) ? T2 : T3;
    for (int p = 0; p < 4; ++p) {
      int idx = p * 256 + tid;
      int row = idx >> 4, c4 = idx & 15;
      float4 v = *(const float4*)&W[(size_t)(k0 + row) * 1024 + n0 + c4 * 4];
      t[row][c4 * 4 + 0] = f2bf(v.x);
      t[row][c4 * 4 + 1] = f2bf(v.y);
      t[row][c4 * 4 + 2] = f2bf(v.z);
      t[row][c4 * 4 + 3] = f2bf(v.w);
    }
    __syncthreads();
    for (int p = 0; p < 2; ++p) {
      int idx = p * 256 + tid;
      int j = idx >> 3, c8 = idx & 7;
      unsigned short tmp[8];
      for (int i = 0; i < 8; ++i) tmp[i] = t[c8 * 8 + i][j];
      uint4 o;
      o.x = tmp[0] | ((unsigned)tmp[1] << 16);
      o.y = tmp[2] | ((unsigned)tmp[3] << 16);
      o.z = tmp[4] | ((unsigned)tmp[5] << 16);
      o.w = tmp[6] | ((unsigned)tmp[7] << 16);
      *(uint4*)&Wt[(size_t)(n0 + j) * 1024 + k0 + c8 * 8] = o;
    }
  } else {
    int g = (bid - 13312) * 256 + tid;          // [0, 2^21)
    int widx = g & 15, hi = (g >> 4) & 1, l31 = (g >> 5) & 31;
    int it = (g >> 10) & 31, rowblk = g >> 15;
    int ni = widx >> 3, kcl = (widx >> 2) & 1, e = widx & 3;
    int kk = 64 * it + 32 * ni + 16 * kcl + 4 * hi + (e >> 1) * 8 + (e & 1) * 2;
    int qrow = rowblk * 32 + l31;
    const int* mrow = mask + (size_t)qrow * 2048 + kk;
    unsigned wd = (mrow[0] ? 0xFFFFu : 0u) | (mrow[1] ? 0xFFFF0000u : 0u);
    bmw[g] = wd;
  }
}

// ---------- fused QKV projection GEMM, 128x128, dbuf 1-barrier, coalesced epi ----------
// z=0: q*(0.125*log2e) -> [B,H,S,HD]; z=1: k -> [B,H,S,HD]; z=2: v -> v^T [B,H,HD,S]
__global__ __launch_bounds__(256) void proj3_kernel(
    const unsigned short* __restrict__ A0, const unsigned short* __restrict__ A1,
    const unsigned short* __restrict__ A2,
    const unsigned short* __restrict__ W0, const unsigned short* __restrict__ W1,
    const unsigned short* __restrict__ W2,
    const float* __restrict__ b0, const float* __restrict__ b1, const float* __restrict__ b2,
    unsigned short* __restrict__ oq, unsigned short* __restrict__ ok,
    unsigned short* __restrict__ ovt) {
  const int z = blockIdx.z;
  const unsigned short* A  = (z == 0) ? A0 : (z == 1) ? A1 : A2;
  const unsigned short* Wt = (z == 0) ? W0 : (z == 1) ? W1 : W2;
  const float* bias        = (z == 0) ? b0 : (z == 1) ? b1 : b2;

  // K-loop dbuf (32KB) aliased with the epilogue tile (34.8KB): LDS = 34.8KB.
  __shared__ __align__(16) union SH {
    struct { unsigned short As[2][4096]; unsigned short Bs[2][4096]; } kb;
    unsigned short Ls[128][136];
  } sh;

  const int tid = threadIdx.x;
  const int lane = tid & 63, w = tid >> 6, ln = lane & 15, quad = lane >> 4;
  const int wm = (w & 1) * 64, wn = (w >> 1) * 64;
  const int m0 = blockIdx.x * 128, n0 = blockIdx.y * 128;

  const int slr = lane >> 2;
  const int schunk = (lane & 3) ^ ((lane >> 3) & 3);
  const int cfrag = (quad ^ ((ln >> 1) & 3)) * 8;

  auto STAGE = [&](int buf, int kt) {
    gll16(&A[(size_t)(m0 + w * 32 + slr) * 1024 + kt + schunk * 8],       &sh.kb.As[buf][(w * 32) * 32]);
    gll16(&A[(size_t)(m0 + w * 32 + 16 + slr) * 1024 + kt + schunk * 8],  &sh.kb.As[buf][(w * 32 + 16) * 32]);
    gll16(&Wt[(size_t)(n0 + w * 32 + slr) * 1024 + kt + schunk * 8],      &sh.kb.Bs[buf][(w * 32) * 32]);
    gll16(&Wt[(size_t)(n0 + w * 32 + 16 + slr) * 1024 + kt + schunk * 8], &sh.kb.Bs[buf][(w * 32 + 16) * 32]);
  };

  f4v zero = {0.f, 0.f, 0.f, 0.f};
  f4v acc[4][4];
  for (int mi = 0; mi < 4; ++mi)
    for (int ni = 0; ni < 4; ++ni) acc[mi][ni] = zero;

  STAGE(0, 0);
  __syncthreads();

  for (int kt = 0; kt < 1024; kt += 32) {
    const int cur = (kt >> 5) & 1;
    if (kt + 32 < 1024) STAGE(cur ^ 1, kt + 32);  // loads covered by this step's compute
    s8v a[4], b[4];
    for (int mi = 0; mi < 4; ++mi) a[mi] = *(const s8v*)&sh.kb.As[cur][(wm + mi * 16 + ln) * 32 + cfrag];
    for (int ni = 0; ni < 4; ++ni) b[ni] = *(const s8v*)&sh.kb.Bs[cur][(wn + ni * 16 + ln) * 32 + cfrag];
    if (z < 2) {
      for (int mi = 0; mi < 4; ++mi)
        for (int ni = 0; ni < 4; ++ni)
          acc[mi][ni] = __builtin_amdgcn_mfma_f32_16x16x32_bf16(a[mi], b[ni], acc[mi][ni], 0, 0, 0);
    } else {
      for (int mi = 0; mi < 4; ++mi)
        for (int ni = 0; ni < 4; ++ni)
          acc[mi][ni] = __builtin_amdgcn_mfma_f32_16x16x32_bf16(b[ni], a[mi], acc[mi][ni], 0, 0, 0);
    }
    __syncthreads();   // reads of buf cur done; STAGE'd loads for cur^1 landed
  }

  // ---- epilogue: dump (bias/scale applied) into Ls, then coalesced 16B stores ----
  if (z < 2) {
    const float qscale = (z == 0) ? 0.18033688f : 1.0f;  // 0.125 * log2(e)
    for (int mi = 0; mi < 4; ++mi) {
      int row = wm + mi * 16 + quad * 4;
      for (int ni = 0; ni < 4; ++ni) {
        int col = wn + ni * 16 + ln;
        float bvv = bias[n0 + col];
        for (int r = 0; r < 4; ++r)
          sh.Ls[row + r][col] = f2bf((acc[mi][ni][r] + bvv) * qscale);
      }
    }
  } else {
    // dump transposed: Ls[tile_col][tile_row] so the store phase is shared
    for (int ni = 0; ni < 4; ++ni) {
      for (int r = 0; r < 4; ++r) {
        int colw = wn + ni * 16 + quad * 4 + r;
        float bvv = bias[n0 + colw];
        for (int mi = 0; mi < 4; ++mi) {
          int rowg = wm + mi * 16 + ln;
          sh.Ls[colw][rowg] = f2bf(acc[mi][ni][r] + bvv);
        }
      }
    }
  }
  __syncthreads();

  if (z < 2) {
    unsigned short* outp = (z == 0) ? oq : ok;
    for (int p = 0; p < 8; ++p) {
      int row = p * 16 + (tid >> 4);       // tile row 0..127 (= s index)
      int cg  = tid & 15;                  // 8-col group
      uint4 vv = *(const uint4*)&sh.Ls[row][cg * 8];
      int rb = m0 + row, b_ = rb >> 11, s = rb & 2047;
      int colg = n0 + cg * 8, h = colg >> 6, hd = colg & 63;
      *(uint4*)&outp[(((size_t)(b_ * 16 + h)) * 2048 + s) * 64 + hd] = vv;
    }
  } else {
    for (int p = 0; p < 8; ++p) {
      int rr = p * 16 + (tid >> 4);        // Ls row = tile col (= hd index)
      int cg = tid & 15;                   // 8 consecutive s
      uint4 vv = *(const uint4*)&sh.Ls[rr][cg * 8];
      int colw = n0 + rr, h = colw >> 6, hd = colw & 63;
      int sg = m0 + cg * 8, b_ = sg >> 11, ss = sg & 2047;
      *(uint4*)&ovt[(((size_t)(b_ * 16 + h)) * 64 + hd) * 2048 + ss] = vv;
    }
  }
}

// ---------- flash attention R13 (best measured): 4 waves x 32 q-rows, pipelined ----------
#define FLASH_ITER(i, SIN0, SIN1, SOUT0, SOUT1)                                 \
  {                                                                             \
    const int cur = (i) & 1;                                                    \
    uint4 nA, nB, nC, nD;                                                       \
    if ((i) < 31) {                                                             \
      const uint4* m4 = (const uint4*)(mwp + ((i) + 1) * 1024);                 \
      nA = m4[0]; nB = m4[1]; nC = m4[2]; nD = m4[3];                           \
    }                                                                           \
    /* S(i+1): issue first so the matrix pipe runs under pack(i)'s VALU */      \
    __builtin_amdgcn_s_setprio(1);                                              \
    if ((i) < 31) {                                                             \
      s8v ak0 = *(const s8v*)&k_s[cur ^ 1][l31][hi * 8];                        \
      s8v ak1 = *(const s8v*)&k_s[cur ^ 1][32 + l31][hi * 8];                   \
      SOUT0 = __builtin_amdgcn_mfma_f32_32x32x16_bf16(ak0, qf[0], zf, 0, 0, 0); \
      SOUT1 = __builtin_amdgcn_mfma_f32_32x32x16_bf16(ak1, qf[0], zf, 0, 0, 0); \
      _Pragma("unroll")                                                         \
      for (int c = 1; c < 4; ++c) {                                             \
        ak0 = *(const s8v*)&k_s[cur ^ 1][l31][c * 16 + hi * 8];                 \
        ak1 = *(const s8v*)&k_s[cur ^ 1][32 + l31][c * 16 + hi * 8];            \
        SOUT0 = __builtin_amdgcn_mfma_f32_32x32x16_bf16(ak0, qf[c], SOUT0, 0, 0, 0); \
        SOUT1 = __builtin_amdgcn_mfma_f32_32x32x16_bf16(ak1, qf[c], SOUT1, 0, 0, 0); \
      }                                                                         \
    }                                                                           \
    __builtin_amdgcn_s_setprio(0);                                              \
    /* pack(i): p = 2^s * maskbit, to bf16 pairs, permlane -> PV A-frags */     \
    s8v pf[4];                                                                  \
    _Pragma("unroll")                                                           \
    for (int ni = 0; ni < 2; ++ni) {                                            \
      const f16v sv = ni ? SIN1 : SIN0;                                         \
      _Pragma("unroll")                                                         \
      for (int kcl = 0; kcl < 2; ++kcl) {                                       \
        const int rb = 8 * kcl;                                                 \
        const uint4 mw = ni ? (kcl ? mwD : mwC) : (kcl ? mwB : mwA);            \
        unsigned x0 = pkbf(__builtin_amdgcn_exp2f(sv[rb + 0]),                  \
                           __builtin_amdgcn_exp2f(sv[rb + 1])) & mw.x;          \
        unsigned x1 = pkbf(__builtin_amdgcn_exp2f(sv[rb + 2]),                  \
                           __builtin_amdgcn_exp2f(sv[rb + 3])) & mw.y;          \
        unsigned y0 = pkbf(__builtin_amdgcn_exp2f(sv[rb + 4]),                  \
                           __builtin_amdgcn_exp2f(sv[rb + 5])) & mw.z;          \
        unsigned y1 = pkbf(__builtin_amdgcn_exp2f(sv[rb + 6]),                  \
                           __builtin_amdgcn_exp2f(sv[rb + 7])) & mw.w;          \
        asm("v_permlane32_swap_b32 %0, %1" : "+v"(x0), "+v"(y0));               \
        asm("v_permlane32_swap_b32 %0, %1" : "+v"(x1), "+v"(y1));               \
        union { uint4 u; s8v v; } cv;                                           \
        cv.u = make_uint4(x0, x1, y0, y1);                                      \
        pf[ni * 2 + kcl] = cv.v;                                                \
      }                                                                         \
    }                                                                           \
    /* PV(i): l += P@ones, O += P@V */                                          \
    __builtin_amdgcn_s_setprio(1);                                              \
    _Pragma("unroll")                                                           \
    for (int kc = 0; kc < 4; ++kc)                                              \
      lac = __builtin_amdgcn_mfma_f32_32x32x16_bf16(pf[kc], ones, lac, 0, 0, 0);\
    _Pragma("unroll")                                                           \
    for (int kc = 0; kc < 4; ++kc) {                                            \
      s8v bv0 = *(const s8v*)&v_s[cur][l31][kc * 16 + hi * 8];                  \
      s8v bv1 = *(const s8v*)&v_s[cur][32 + l31][kc * 16 + hi * 8];             \
      o0 = __builtin_amdgcn_mfma_f32_32x32x16_bf16(pf[kc], bv0, o0, 0, 0, 0);   \
      o1 = __builtin_amdgcn_mfma_f32_32x32x16_bf16(pf[kc], bv1, o1, 0, 0, 0);   \
    }                                                                           \
    __builtin_amdgcn_s_setprio(0);                                              \
    __syncthreads();                     /* A: V(i)/K(i+1) reads done */        \
    if ((i) < 30) WRITET(cur);           /* tile i+2 -> buf cur */              \
    if ((i) < 29) LOADT((i) + 3);                                               \
    __syncthreads();                     /* B: tile i+2 visible for iter i+1 */ \
    mwA = nA; mwB = nB; mwC = nC; mwD = nD;                                     \
  }

__global__ __launch_bounds__(256, 2) void flash_kernel(
    const unsigned short* __restrict__ q, const unsigned short* __restrict__ k,
    const unsigned short* __restrict__ vt, const unsigned* __restrict__ bmw,
    unsigned short* __restrict__ ctx) {
  __shared__ __align__(16) unsigned short k_s[2][64][72];
  __shared__ __align__(16) unsigned short v_s[2][64][72];

  const int tid = threadIdx.x;
  const int lane = tid & 63, w = tid >> 6;
  const int l31 = lane & 31, hi = lane >> 5;
  const int q0 = blockIdx.x * 128;
  const int bh = blockIdx.y;
  const unsigned short* qg  = q  + ((size_t)bh * 2048 + q0) * 64;
  const unsigned short* kgb = k  + (size_t)bh * 2048 * 64;
  const unsigned short* vgb = vt + (size_t)bh * 64 * 2048;
  // mask-word base for this lane: bmw[rowblk][it][l31][hi][16]
  const unsigned* mwp = bmw + (size_t)(blockIdx.x * 4 + w) * 32768 + l31 * 32 + hi * 16;

  // Q fragments direct from global: wave w owns q-rows [w*32, w*32+32)
  const int qrow = w * 32 + l31;
  s8v qf[4];
#pragma unroll
  for (int c = 0; c < 4; ++c)
    qf[c] = *(const s8v*)&qg[(size_t)qrow * 64 + c * 16 + hi * 8];

  s8v ones;
#pragma unroll
  for (int i = 0; i < 8; ++i) ones[i] = (short)0x3F80;
  f16v zf;
#pragma unroll
  for (int i = 0; i < 16; ++i) zf[i] = 0.f;

  // staging: 256 threads x 4 uint4 (one K tile + one V tile)
  const int srow = tid >> 3, sc8 = tid & 7;  // rows srow and srow+32

  uint4 kr0, kr1, vr0, vr1;
  auto LOADT = [&](int it) {
    const int kk = it * 64;
    kr0 = *(const uint4*)&kgb[(size_t)(kk + srow) * 64 + sc8 * 8];
    kr1 = *(const uint4*)&kgb[(size_t)(kk + srow + 32) * 64 + sc8 * 8];
    vr0 = *(const uint4*)&vgb[(size_t)srow * 2048 + kk + sc8 * 8];
    vr1 = *(const uint4*)&vgb[(size_t)(srow + 32) * 2048 + kk + sc8 * 8];
  };
  auto WRITET = [&](int b) {
    *(uint4*)&k_s[b][srow][sc8 * 8] = kr0;
    *(uint4*)&k_s[b][srow + 32][sc8 * 8] = kr1;
    *(uint4*)&v_s[b][srow][sc8 * 8] = vr0;
    *(uint4*)&v_s[b][srow + 32][sc8 * 8] = vr1;
  };

  LOADT(0); WRITET(0);
  LOADT(1); WRITET(1);
  LOADT(2);
  __syncthreads();

  // mask words for tile 0
  uint4 mwA, mwB, mwC, mwD;
  {
    const uint4* m4 = (const uint4*)mwp;
    mwA = m4[0]; mwB = m4[1]; mwC = m4[2]; mwD = m4[3];
  }

  // S(0) from k_s[0]
  f16v sA0, sA1, sB0, sB1;
  {
    s8v ak0 = *(const s8v*)&k_s[0][l31][hi * 8];
    s8v ak1 = *(const s8v*)&k_s[0][32 + l31][hi * 8];
    sA0 = __builtin_amdgcn_mfma_f32_32x32x16_bf16(ak0, qf[0], zf, 0, 0, 0);
    sA1 = __builtin_amdgcn_mfma_f32_32x32x16_bf16(ak1, qf[0], zf, 0, 0, 0);
#pragma unroll
    for (int c = 1; c < 4; ++c) {
      ak0 = *(const s8v*)&k_s[0][l31][c * 16 + hi * 8];
      ak1 = *(const s8v*)&k_s[0][32 + l31][c * 16 + hi * 8];
      sA0 = __builtin_amdgcn_mfma_f32_32x32x16_bf16(ak0, qf[c], sA0, 0, 0, 0);
      sA1 = __builtin_amdgcn_mfma_f32_32x32x16_bf16(ak1, qf[c], sA1, 0, 0, 0);
    }
  }

  f16v o0, o1, lac;
#pragma unroll
  for (int i = 0; i < 16; ++i) { o0[i] = 0.f; o1[i] = 0.f; lac[i] = 0.f; }

  for (int ii = 0; ii < 16; ++ii) {
    const int i0 = ii * 2;
    FLASH_ITER(i0,     sA0, sA1, sB0, sB1);
    FLASH_ITER(i0 + 1, sB0, sB1, sA0, sA1);
  }

  // O row r -> q_local=(r&3)+8*(r>>2)+4*hi, col=lane&31 (+32 for o1)
  const int b_ = bh >> 4, h = bh & 15;
#pragma unroll
  for (int r = 0; r < 16; ++r) {
    const int ql = (r & 3) + 8 * (r >> 2) + 4 * hi;
    const float inv = 1.f / lac[r];
    const int srw = q0 + w * 32 + ql;
    const size_t base = ((size_t)b_ * 2048 + srw) * 1024 + h * 64;
    ctx[base + l31] = f2bf(o0[r] * inv);
    ctx[base + 32 + l31] = f2bf(o1[r] * inv);
  }
}

// ---------- output projection, 128x128 tile, dbuf 1-barrier ----------
__global__ __launch_bounds__(256) void gemm_out_kernel(
    const unsigned short* __restrict__ A, const unsigned short* __restrict__ Wt,
    const float* __restrict__ bias, float* __restrict__ out) {
  __shared__ __align__(16) unsigned short As[2][4096];
  __shared__ __align__(16) unsigned short Bs[2][4096];

  const int tid = threadIdx.x;
  const int lane = tid & 63, w = tid >> 6, ln = lane & 15, quad = lane >> 4;
  const int wm = (w & 1) * 64, wn = (w >> 1) * 64;
  const int m0 = blockIdx.x * 128, n0 = blockIdx.y * 128;

  const int slr = lane >> 2;
  const int schunk = (lane & 3) ^ ((lane >> 3) & 3);
  const int cfrag = (quad ^ ((ln >> 1) & 3)) * 8;

  auto STAGE = [&](int buf, int kt) {
    gll16(&A[(size_t)(m0 + w * 32 + slr) * 1024 + kt + schunk * 8],       &As[buf][(w * 32) * 32]);
    gll16(&A[(size_t)(m0 + w * 32 + 16 + slr) * 1024 + kt + schunk * 8],  &As[buf][(w * 32 + 16) * 32]);
    gll16(&Wt[(size_t)(n0 + w * 32 + slr) * 1024 + kt + schunk * 8],      &Bs[buf][(w * 32) * 32]);
    gll16(&Wt[(size_t)(n0 + w * 32 + 16 + slr) * 1024 + kt + schunk * 8], &Bs[buf][(w * 32 + 16) * 32]);
  };

  f4v zero = {0.f, 0.f, 0.f, 0.f};
  f4v acc[4][4];
  for (int mi = 0; mi < 4; ++mi)
    for (int ni = 0; ni < 4; ++ni) acc[mi][ni] = zero;

  STAGE(0, 0);
  __syncthreads();

  for (int kt = 0; kt < 1024; kt += 32) {
    const int cur = (kt >> 5) & 1;
    if (kt + 32 < 1024) STAGE(cur ^ 1, kt + 32);
    s8v a[4], b[4];
    for (int mi = 0; mi < 4; ++mi) a[mi] = *(const s8v*)&As[cur][(wm + mi * 16 + ln) * 32 + cfrag];
    for (int ni = 0; ni < 4; ++ni) b[ni] = *(const s8v*)&Bs[cur][(wn + ni * 16 + ln) * 32 + cfrag];
    for (int mi = 0; mi < 4; ++mi)
      for (int ni = 0; ni < 4; ++ni)
        acc[mi][ni] = __builtin_amdgcn_mfma_f32_16x16x32_bf16(a[mi], b[ni], acc[mi][ni], 0, 0, 0);
    __syncthreads();
  }

  for (int mi = 0; mi < 4; ++mi) {
    int rb = m0 + wm + mi * 16 + quad * 4;
    for (int ni = 0; ni < 4; ++ni) {
      int col = n0 + wn + ni * 16 + ln;
      float bvv = bias[col];
      for (int r = 0; r < 4; ++r)
        out[(size_t)(rb + r) * 1024 + col] = acc[mi][ni][r] + bvv;
    }
  }
}

extern "C" void kernel_launch(void* const* d_in, const int* in_sizes, int n_in,
                              void* d_out, int out_size, void* d_ws, size_t ws_size,
                              hipStream_t stream) {
  const float* Q  = (const float*)d_in[0];
  const float* K  = (const float*)d_in[1];
  const float* V  = (const float*)d_in[2];
  const int* mask = (const int*)d_in[3];
  const float* Wq = (const float*)d_in[4];
  const float* bq = (const float*)d_in[5];
  const float* Wk = (const float*)d_in[6];
  const float* bk = (const float*)d_in[7];
  const float* Wv = (const float*)d_in[8];
  const float* bv = (const float*)d_in[9];
  const float* Wo = (const float*)d_in[10];
  const float* bo = (const float*)d_in[11];
  float* out = (float*)d_out;

  char* ws = (char*)d_ws;
  const size_t MB = 1u << 20;
  unsigned short* qb  = (unsigned short*)(ws + 0 * MB);
  unsigned short* kb  = (unsigned short*)(ws + 8 * MB);
  unsigned short* vb  = (unsigned short*)(ws + 16 * MB);
  unsigned short* wqt = (unsigned short*)(ws + 24 * MB);
  unsigned short* wkt = (unsigned short*)(ws + 26 * MB);
  unsigned short* wvt = (unsigned short*)(ws + 28 * MB);
  unsigned short* wot = (unsigned short*)(ws + 30 * MB);
  unsigned short* qh  = (unsigned short*)(ws + 32 * MB);
  unsigned short* kh  = (unsigned short*)(ws + 40 * MB);
  unsigned short* vth = (unsigned short*)(ws + 48 * MB);
  unsigned* bmw       = (unsigned*)(ws + 56 * MB);       // 8 MB of packed mask words
  unsigned short* ctx = (unsigned short*)(ws + 16 * MB);  // aliases vb (dead after proj3)

  prep_kernel<<<21504, 256, 0, stream>>>(Q, K, V, qb, kb, vb,
                                         Wq, Wk, Wv, Wo, wqt, wkt, wvt, wot,
                                         mask, bmw);
  proj3_kernel<<<dim3(32, 8, 3), 256, 0, stream>>>(qb, kb, vb, wqt, wkt, wvt,
                                                   bq, bk, bv, qh, kh, vth);
  flash_kernel<<<dim3(16, 32), 256, 0, stream>>>(qh, kh, vth, bmw, ctx);
  gemm_out_kernel<<<dim3(32, 8), 256, 0, stream>>>(ctx, wot, bo, out);
}

// Round 11
// 242.478 us; speedup vs baseline: 1.4188x; 1.0199x over previous
//
#include <hip/hip_runtime.h>

// MHA: B=2, S=2048, D=1024, H=16, HD=64. fp32 in/out, bf16 MFMA internally.
// ws layout (64 MB): qb/kb/vb bf16 [4096,1024] @0/8/16MB; Wq/k/v/o^T bf16
// [1024,1024] @24/26/28/30MB; q(pre-scaled 0.125*log2e),k [B,H,S,HD] @32/40MB;
// v^T [B,H,HD,S] @48MB; bmw u32 mask-words @56MB (8MB); ctx bf16 @16MB.
//
// R20: proj3 still latency-bound at 59us (MfmaUtil 16%): __syncthreads emits a
// full vmcnt(0) drain, so each step's gll16s must land with only ~400cyc cover.
// Fix = T3/T4 counted-vmcnt (m218: counted-vs-drain0 +38-73%): 3-buffer LDS;
// per step: STAGE(step+2) -> compute buf[step] -> s_waitcnt vmcnt(4) (waits
// only the PREVIOUS set, which has 2 steps of cover; just-issued set stays in
// flight) -> raw s_barrier (no drain) -> sched_barrier(0). Same loop for
// gemm_out at 64x128 (512 blocks = 2/CU, vmcnt(3)). Flash (R13) + prep
// untouched.

using s8v = __attribute__((ext_vector_type(8))) short;   // 8 bf16 (4 VGPRs)
using f4v = __attribute__((ext_vector_type(4))) float;   // MFMA acc (16x16)
using f16v = __attribute__((ext_vector_type(16))) float; // MFMA acc (32x32)
typedef unsigned long long u64;

__device__ __forceinline__ unsigned short f2bf(float f) {
  union { float f; unsigned int u; } v; v.f = f;
  return (unsigned short)((v.u + 0x7fffu + ((v.u >> 16) & 1u)) >> 16);  // RNE
}

// pack two f32 -> two bf16 (truncation): lo | hi<<16
__device__ __forceinline__ unsigned pkbf(float lo, float hi2) {
  return __builtin_amdgcn_perm(__float_as_uint(hi2), __float_as_uint(lo), 0x07060302);
}

__device__ __forceinline__ void gll16(const void* g, void* l) {
  __builtin_amdgcn_global_load_lds(
      (const __attribute__((address_space(1))) unsigned int*)g,
      (__attribute__((address_space(3))) unsigned int*)l, 16, 0, 0);
}

// ---------- merged prep: f2b (QKV), wtrans (4 weights), packed mask words ----------
__global__ void prep_kernel(const float* __restrict__ Q, const float* __restrict__ K,
                            const float* __restrict__ V,
                            unsigned short* __restrict__ qb, unsigned short* __restrict__ kb,
                            unsigned short* __restrict__ vb,
                            const float* __restrict__ W0, const float* __restrict__ W1,
                            const float* __restrict__ W2, const float* __restrict__ W3,
                            unsigned short* __restrict__ T0, unsigned short* __restrict__ T1,
                            unsigned short* __restrict__ T2, unsigned short* __restrict__ T3,
                            const int* __restrict__ mask, unsigned* __restrict__ bmw) {
  __shared__ unsigned short t[64][72];
  const int bid = blockIdx.x, tid = threadIdx.x;
  if (bid < 12288) {
    int z = bid >> 12;
    int idx = (bid & 4095) * 256 + tid;
    const float* in = (z == 0) ? Q : (z == 1) ? K : V;
    unsigned short* out = (z == 0) ? qb : (z == 1) ? kb : vb;
    float4 v = ((const float4*)in)[idx];
    ushort4 o;
    o.x = f2bf(v.x); o.y = f2bf(v.y); o.z = f2bf(v.z); o.w = f2bf(v.w);
    ((ushort4*)out)[idx] = o;
  } else if (bid < 13312) {
    int b = bid - 12288;
    int z = b >> 8, rem = b & 255;
    int k0 = (rem >> 4) * 64, n0 = (rem & 15) * 64;
    const float* W = (z == 0) ? W0 : (z == 1) ? W1 : (z == 2) ? W2 : W3;
    unsigned short* Wt = (z == 0) ? T0 : (z == 1) ? T1 : (z == 2) ? T2 : T3;
    for (int p = 0; p < 4; ++p) {
      int idx = p * 256 + tid;
      int row = idx >> 4, c4 = idx & 15;
      float4 v = *(const float4*)&W[(size_t)(k0 + row) * 1024 + n0 + c4 * 4];
      t[row][c4 * 4 + 0] = f2bf(v.x);
      t[row][c4 * 4 + 1] = f2bf(v.y);
      t[row][c4 * 4 + 2] = f2bf(v.z);
      t[row][c4 * 4 + 3] = f2bf(v.w);
    }
    __syncthreads();
    for (int p = 0; p < 2; ++p) {
      int idx = p * 256 + tid;
      int j = idx >> 3, c8 = idx & 7;
      unsigned short tmp[8];
      for (int i = 0; i < 8; ++i) tmp[i] = t[c8 * 8 + i][j];
      uint4 o;
      o.x = tmp[0] | ((unsigned)tmp[1] << 16);
      o.y = tmp[2] | ((unsigned)tmp[3] << 16);
      o.z = tmp[4] | ((unsigned)tmp[5] << 16);
      o.w = tmp[6] | ((unsigned)tmp[7] << 16);
      *(uint4*)&Wt[(size_t)(n0 + j) * 1024 + k0 + c8 * 8] = o;
    }
  } else {
    int g = (bid - 13312) * 256 + tid;          // [0, 2^21)
    int widx = g & 15, hi = (g >> 4) & 1, l31 = (g >> 5) & 31;
    int it = (g >> 10) & 31, rowblk = g >> 15;
    int ni = widx >> 3, kcl = (widx >> 2) & 1, e = widx & 3;
    int kk = 64 * it + 32 * ni + 16 * kcl + 4 * hi + (e >> 1) * 8 + (e & 1) * 2;
    int qrow = rowblk * 32 + l31;
    const int* mrow = mask + (size_t)qrow * 2048 + kk;
    unsigned wd = (mrow[0] ? 0xFFFFu : 0u) | (mrow[1] ? 0xFFFF0000u : 0u);
    bmw[g] = wd;
  }
}

// ---------- fused QKV projection GEMM, 128x128, 3-buf counted-vmcnt ----------
// z=0: q*(0.125*log2e) -> [B,H,S,HD]; z=1: k -> [B,H,S,HD]; z=2: v -> v^T [B,H,HD,S]
__global__ __launch_bounds__(256) void proj3_kernel(
    const unsigned short* __restrict__ A0, const unsigned short* __restrict__ A1,
    const unsigned short* __restrict__ A2,
    const unsigned short* __restrict__ W0, const unsigned short* __restrict__ W1,
    const unsigned short* __restrict__ W2,
    const float* __restrict__ b0, const float* __restrict__ b1, const float* __restrict__ b2,
    unsigned short* __restrict__ oq, unsigned short* __restrict__ ok,
    unsigned short* __restrict__ ovt) {
  const int z = blockIdx.z;
  const unsigned short* A  = (z == 0) ? A0 : (z == 1) ? A1 : A2;
  const unsigned short* Wt = (z == 0) ? W0 : (z == 1) ? W1 : W2;
  const float* bias        = (z == 0) ? b0 : (z == 1) ? b1 : b2;

  // 3 K-step buffers (As 8KB + Bs 8KB each = 48KB), unioned with epilogue tile.
  __shared__ __align__(16) union SH {
    unsigned short KB[3][8192];            // [buf][ As 0..4095 | Bs 4096..8191 ]
    unsigned short Ls[128][136];
  } sh;

  const int tid = threadIdx.x;
  const int lane = tid & 63, w = tid >> 6, ln = lane & 15, quad = lane >> 4;
  const int wm = (w & 1) * 64, wn = (w >> 1) * 64;
  const int m0 = blockIdx.x * 128, n0 = blockIdx.y * 128;

  const int slr = lane >> 2;
  const int schunk = (lane & 3) ^ ((lane >> 3) & 3);
  const int cfrag = (quad ^ ((ln >> 1) & 3)) * 8;

  auto STAGE = [&](int buf, int kt) {
    gll16(&A[(size_t)(m0 + w * 32 + slr) * 1024 + kt + schunk * 8],       &sh.KB[buf][(w * 32) * 32]);
    gll16(&A[(size_t)(m0 + w * 32 + 16 + slr) * 1024 + kt + schunk * 8],  &sh.KB[buf][(w * 32 + 16) * 32]);
    gll16(&Wt[(size_t)(n0 + w * 32 + slr) * 1024 + kt + schunk * 8],      &sh.KB[buf][4096 + (w * 32) * 32]);
    gll16(&Wt[(size_t)(n0 + w * 32 + 16 + slr) * 1024 + kt + schunk * 8], &sh.KB[buf][4096 + (w * 32 + 16) * 32]);
  };

  f4v zero = {0.f, 0.f, 0.f, 0.f};
  f4v acc[4][4];
  for (int mi = 0; mi < 4; ++mi)
    for (int ni = 0; ni < 4; ++ni) acc[mi][ni] = zero;

  STAGE(0, 0);
  STAGE(1, 32);
  asm volatile("s_waitcnt vmcnt(4)" ::: "memory");   // set{0} landed; set{1} in flight
  __builtin_amdgcn_s_barrier();
  __builtin_amdgcn_sched_barrier(0);

  int cur = 0;
  for (int step = 0; step < 32; ++step) {
    if (step < 30) {
      const int nb = (cur == 0) ? 2 : cur - 1;     // (step+2) % 3
      STAGE(nb, step * 32 + 64);
    }
    const unsigned short* Asb = &sh.KB[cur][0];
    const unsigned short* Bsb = &sh.KB[cur][4096];
    s8v a[4], b[4];
    for (int mi = 0; mi < 4; ++mi) a[mi] = *(const s8v*)&Asb[(wm + mi * 16 + ln) * 32 + cfrag];
    for (int ni = 0; ni < 4; ++ni) b[ni] = *(const s8v*)&Bsb[(wn + ni * 16 + ln) * 32 + cfrag];
    if (z < 2) {
      for (int mi = 0; mi < 4; ++mi)
        for (int ni = 0; ni < 4; ++ni)
          acc[mi][ni] = __builtin_amdgcn_mfma_f32_16x16x32_bf16(a[mi], b[ni], acc[mi][ni], 0, 0, 0);
    } else {
      for (int mi = 0; mi < 4; ++mi)
        for (int ni = 0; ni < 4; ++ni)
          acc[mi][ni] = __builtin_amdgcn_mfma_f32_16x16x32_bf16(b[ni], a[mi], acc[mi][ni], 0, 0, 0);
    }
    // Counted wait: previous step's set must have landed (2 steps of cover);
    // the set just issued stays in flight across the raw barrier.
    if (step < 30)       asm volatile("s_waitcnt vmcnt(4)" ::: "memory");
    else if (step == 30) asm volatile("s_waitcnt vmcnt(0)" ::: "memory");
    if (step < 31) {
      __builtin_amdgcn_s_barrier();
      __builtin_amdgcn_sched_barrier(0);
    }
    cur = (cur == 2) ? 0 : cur + 1;
  }
  __syncthreads();   // all frag reads done before Ls (aliases KB) is written

  // ---- epilogue: dump (bias/scale applied) into Ls, then coalesced 16B stores ----
  if (z < 2) {
    const float qscale = (z == 0) ? 0.18033688f : 1.0f;  // 0.125 * log2(e)
    for (int mi = 0; mi < 4; ++mi) {
      int row = wm + mi * 16 + quad * 4;
      for (int ni = 0; ni < 4; ++ni) {
        int col = wn + ni * 16 + ln;
        float bvv = bias[n0 + col];
        for (int r = 0; r < 4; ++r)
          sh.Ls[row + r][col] = f2bf((acc[mi][ni][r] + bvv) * qscale);
      }
    }
  } else {
    // dump transposed: Ls[tile_col][tile_row] so the store phase is shared
    for (int ni = 0; ni < 4; ++ni) {
      for (int r = 0; r < 4; ++r) {
        int colw = wn + ni * 16 + quad * 4 + r;
        float bvv = bias[n0 + colw];
        for (int mi = 0; mi < 4; ++mi) {
          int rowg = wm + mi * 16 + ln;
          sh.Ls[colw][rowg] = f2bf(acc[mi][ni][r] + bvv);
        }
      }
    }
  }
  __syncthreads();

  if (z < 2) {
    unsigned short* outp = (z == 0) ? oq : ok;
    for (int p = 0; p < 8; ++p) {
      int row = p * 16 + (tid >> 4);       // tile row 0..127 (= s index)
      int cg  = tid & 15;                  // 8-col group
      uint4 vv = *(const uint4*)&sh.Ls[row][cg * 8];
      int rb = m0 + row, b_ = rb >> 11, s = rb & 2047;
      int colg = n0 + cg * 8, h = colg >> 6, hd = colg & 63;
      *(uint4*)&outp[(((size_t)(b_ * 16 + h)) * 2048 + s) * 64 + hd] = vv;
    }
  } else {
    for (int p = 0; p < 8; ++p) {
      int rr = p * 16 + (tid >> 4);        // Ls row = tile col (= hd index)
      int cg = tid & 15;                   // 8 consecutive s
      uint4 vv = *(const uint4*)&sh.Ls[rr][cg * 8];
      int colw = n0 + rr, h = colw >> 6, hd = colw & 63;
      int sg = m0 + cg * 8, b_ = sg >> 11, ss = sg & 2047;
      *(uint4*)&ovt[(((size_t)(b_ * 16 + h)) * 64 + hd) * 2048 + ss] = vv;
    }
  }
}

// ---------- flash attention R13 (best measured): 4 waves x 32 q-rows, pipelined ----------
#define FLASH_ITER(i, SIN0, SIN1, SOUT0, SOUT1)                                 \
  {                                                                             \
    const int cur = (i) & 1;                                                    \
    uint4 nA, nB, nC, nD;                                                       \
    if ((i) < 31) {                                                             \
      const uint4* m4 = (const uint4*)(mwp + ((i) + 1) * 1024);                 \
      nA = m4[0]; nB = m4[1]; nC = m4[2]; nD = m4[3];                           \
    }                                                                           \
    /* S(i+1): issue first so the matrix pipe runs under pack(i)'s VALU */      \
    __builtin_amdgcn_s_setprio(1);                                              \
    if ((i) < 31) {                                                             \
      s8v ak0 = *(const s8v*)&k_s[cur ^ 1][l31][hi * 8];                        \
      s8v ak1 = *(const s8v*)&k_s[cur ^ 1][32 + l31][hi * 8];                   \
      SOUT0 = __builtin_amdgcn_mfma_f32_32x32x16_bf16(ak0, qf[0], zf, 0, 0, 0); \
      SOUT1 = __builtin_amdgcn_mfma_f32_32x32x16_bf16(ak1, qf[0], zf, 0, 0, 0); \
      _Pragma("unroll")                                                         \
      for (int c = 1; c < 4; ++c) {                                             \
        ak0 = *(const s8v*)&k_s[cur ^ 1][l31][c * 16 + hi * 8];                 \
        ak1 = *(const s8v*)&k_s[cur ^ 1][32 + l31][c * 16 + hi * 8];            \
        SOUT0 = __builtin_amdgcn_mfma_f32_32x32x16_bf16(ak0, qf[c], SOUT0, 0, 0, 0); \
        SOUT1 = __builtin_amdgcn_mfma_f32_32x32x16_bf16(ak1, qf[c], SOUT1, 0, 0, 0); \
      }                                                                         \
    }                                                                           \
    __builtin_amdgcn_s_setprio(0);                                              \
    /* pack(i): p = 2^s * maskbit, to bf16 pairs, permlane -> PV A-frags */     \
    s8v pf[4];                                                                  \
    _Pragma("unroll")                                                           \
    for (int ni = 0; ni < 2; ++ni) {                                            \
      const f16v sv = ni ? SIN1 : SIN0;                                         \
      _Pragma("unroll")                                                         \
      for (int kcl = 0; kcl < 2; ++kcl) {                                       \
        const int rb = 8 * kcl;                                                 \
        const uint4 mw = ni ? (kcl ? mwD : mwC) : (kcl ? mwB : mwA);            \
        unsigned x0 = pkbf(__builtin_amdgcn_exp2f(sv[rb + 0]),                  \
                           __builtin_amdgcn_exp2f(sv[rb + 1])) & mw.x;          \
        unsigned x1 = pkbf(__builtin_amdgcn_exp2f(sv[rb + 2]),                  \
                           __builtin_amdgcn_exp2f(sv[rb + 3])) & mw.y;          \
        unsigned y0 = pkbf(__builtin_amdgcn_exp2f(sv[rb + 4]),                  \
                           __builtin_amdgcn_exp2f(sv[rb + 5])) & mw.z;          \
        unsigned y1 = pkbf(__builtin_amdgcn_exp2f(sv[rb + 6]),                  \
                           __builtin_amdgcn_exp2f(sv[rb + 7])) & mw.w;          \
        asm("v_permlane32_swap_b32 %0, %1" : "+v"(x0), "+v"(y0));               \
        asm("v_permlane32_swap_b32 %0, %1" : "+v"(x1), "+v"(y1));               \
        union { uint4 u; s8v v; } cv;                                           \
        cv.u = make_uint4(x0, x1, y0, y1);                                      \
        pf[ni * 2 + kcl] = cv.v;                                                \
      }                                                                         \
    }                                                                           \
    /* PV(i): l += P@ones, O += P@V */                                          \
    __builtin_amdgcn_s_setprio(1);                                              \
    _Pragma("unroll")                                                           \
    for (int kc = 0; kc < 4; ++kc)                                              \
      lac = __builtin_amdgcn_mfma_f32_32x32x16_bf16(pf[kc], ones, lac, 0, 0, 0);\
    _Pragma("unroll")                                                           \
    for (int kc = 0; kc < 4; ++kc) {                                            \
      s8v bv0 = *(const s8v*)&v_s[cur][l31][kc * 16 + hi * 8];                  \
      s8v bv1 = *(const s8v*)&v_s[cur][32 + l31][kc * 16 + hi * 8];             \
      o0 = __builtin_amdgcn_mfma_f32_32x32x16_bf16(pf[kc], bv0, o0, 0, 0, 0);   \
      o1 = __builtin_amdgcn_mfma_f32_32x32x16_bf16(pf[kc], bv1, o1, 0, 0, 0);   \
    }                                                                           \
    __builtin_amdgcn_s_setprio(0);                                              \
    __syncthreads();                     /* A: V(i)/K(i+1) reads done */        \
    if ((i) < 30) WRITET(cur);           /* tile i+2 -> buf cur */              \
    if ((i) < 29) LOADT((i) + 3);                                               \
    __syncthreads();                     /* B: tile i+2 visible for iter i+1 */ \
    mwA = nA; mwB = nB; mwC = nC; mwD = nD;                                     \
  }

__global__ __launch_bounds__(256, 2) void flash_kernel(
    const unsigned short* __restrict__ q, const unsigned short* __restrict__ k,
    const unsigned short* __restrict__ vt, const unsigned* __restrict__ bmw,
    unsigned short* __restrict__ ctx) {
  __shared__ __align__(16) unsigned short k_s[2][64][72];
  __shared__ __align__(16) unsigned short v_s[2][64][72];

  const int tid = threadIdx.x;
  const int lane = tid & 63, w = tid >> 6;
  const int l31 = lane & 31, hi = lane >> 5;
  const int q0 = blockIdx.x * 128;
  const int bh = blockIdx.y;
  const unsigned short* qg  = q  + ((size_t)bh * 2048 + q0) * 64;
  const unsigned short* kgb = k  + (size_t)bh * 2048 * 64;
  const unsigned short* vgb = vt + (size_t)bh * 64 * 2048;
  // mask-word base for this lane: bmw[rowblk][it][l31][hi][16]
  const unsigned* mwp = bmw + (size_t)(blockIdx.x * 4 + w) * 32768 + l31 * 32 + hi * 16;

  // Q fragments direct from global: wave w owns q-rows [w*32, w*32+32)
  const int qrow = w * 32 + l31;
  s8v qf[4];
#pragma unroll
  for (int c = 0; c < 4; ++c)
    qf[c] = *(const s8v*)&qg[(size_t)qrow * 64 + c * 16 + hi * 8];

  s8v ones;
#pragma unroll
  for (int i = 0; i < 8; ++i) ones[i] = (short)0x3F80;
  f16v zf;
#pragma unroll
  for (int i = 0; i < 16; ++i) zf[i] = 0.f;

  // staging: 256 threads x 4 uint4 (one K tile + one V tile)
  const int srow = tid >> 3, sc8 = tid & 7;  // rows srow and srow+32

  uint4 kr0, kr1, vr0, vr1;
  auto LOADT = [&](int it) {
    const int kk = it * 64;
    kr0 = *(const uint4*)&kgb[(size_t)(kk + srow) * 64 + sc8 * 8];
    kr1 = *(const uint4*)&kgb[(size_t)(kk + srow + 32) * 64 + sc8 * 8];
    vr0 = *(const uint4*)&vgb[(size_t)srow * 2048 + kk + sc8 * 8];
    vr1 = *(const uint4*)&vgb[(size_t)(srow + 32) * 2048 + kk + sc8 * 8];
  };
  auto WRITET = [&](int b) {
    *(uint4*)&k_s[b][srow][sc8 * 8] = kr0;
    *(uint4*)&k_s[b][srow + 32][sc8 * 8] = kr1;
    *(uint4*)&v_s[b][srow][sc8 * 8] = vr0;
    *(uint4*)&v_s[b][srow + 32][sc8 * 8] = vr1;
  };

  LOADT(0); WRITET(0);
  LOADT(1); WRITET(1);
  LOADT(2);
  __syncthreads();

  // mask words for tile 0
  uint4 mwA, mwB, mwC, mwD;
  {
    const uint4* m4 = (const uint4*)mwp;
    mwA = m4[0]; mwB = m4[1]; mwC = m4[2]; mwD = m4[3];
  }

  // S(0) from k_s[0]
  f16v sA0, sA1, sB0, sB1;
  {
    s8v ak0 = *(const s8v*)&k_s[0][l31][hi * 8];
    s8v ak1 = *(const s8v*)&k_s[0][32 + l31][hi * 8];
    sA0 = __builtin_amdgcn_mfma_f32_32x32x16_bf16(ak0, qf[0], zf, 0, 0, 0);
    sA1 = __builtin_amdgcn_mfma_f32_32x32x16_bf16(ak1, qf[0], zf, 0, 0, 0);
#pragma unroll
    for (int c = 1; c < 4; ++c) {
      ak0 = *(const s8v*)&k_s[0][l31][c * 16 + hi * 8];
      ak1 = *(const s8v*)&k_s[0][32 + l31][c * 16 + hi * 8];
      sA0 = __builtin_amdgcn_mfma_f32_32x32x16_bf16(ak0, qf[c], sA0, 0, 0, 0);
      sA1 = __builtin_amdgcn_mfma_f32_32x32x16_bf16(ak1, qf[c], sA1, 0, 0, 0);
    }
  }

  f16v o0, o1, lac;
#pragma unroll
  for (int i = 0; i < 16; ++i) { o0[i] = 0.f; o1[i] = 0.f; lac[i] = 0.f; }

  for (int ii = 0; ii < 16; ++ii) {
    const int i0 = ii * 2;
    FLASH_ITER(i0,     sA0, sA1, sB0, sB1);
    FLASH_ITER(i0 + 1, sB0, sB1, sA0, sA1);
  }

  // O row r -> q_local=(r&3)+8*(r>>2)+4*hi, col=lane&31 (+32 for o1)
  const int b_ = bh >> 4, h = bh & 15;
#pragma unroll
  for (int r = 0; r < 16; ++r) {
    const int ql = (r & 3) + 8 * (r >> 2) + 4 * hi;
    const float inv = 1.f / lac[r];
    const int srw = q0 + w * 32 + ql;
    const size_t base = ((size_t)b_ * 2048 + srw) * 1024 + h * 64;
    ctx[base + l31] = f2bf(o0[r] * inv);
    ctx[base + 32 + l31] = f2bf(o1[r] * inv);
  }
}

// ---------- output projection, 64x128 tile, 3-buf counted-vmcnt ----------
__global__ __launch_bounds__(256) void gemm_out_kernel(
    const unsigned short* __restrict__ A, const unsigned short* __restrict__ Wt,
    const float* __restrict__ bias, float* __restrict__ out) {
  __shared__ __align__(16) unsigned short As[3][2048];
  __shared__ __align__(16) unsigned short Bs[3][4096];

  const int tid = threadIdx.x;
  const int lane = tid & 63, w = tid >> 6, ln = lane & 15, quad = lane >> 4;
  const int wm = (w & 1) * 32, wn = (w >> 1) * 64;
  const int m0 = blockIdx.x * 64, n0 = blockIdx.y * 128;

  const int slr = lane >> 2;
  const int schunk = (lane & 3) ^ ((lane >> 3) & 3);
  const int cfrag = (quad ^ ((ln >> 1) & 3)) * 8;

  auto STAGE = [&](int buf, int kt) {
    gll16(&A[(size_t)(m0 + w * 16 + slr) * 1024 + kt + schunk * 8],       &As[buf][(w * 16) * 32]);
    gll16(&Wt[(size_t)(n0 + w * 32 + slr) * 1024 + kt + schunk * 8],      &Bs[buf][(w * 32) * 32]);
    gll16(&Wt[(size_t)(n0 + w * 32 + 16 + slr) * 1024 + kt + schunk * 8], &Bs[buf][(w * 32 + 16) * 32]);
  };

  f4v zero = {0.f, 0.f, 0.f, 0.f};
  f4v acc[2][4];
  for (int mi = 0; mi < 2; ++mi)
    for (int ni = 0; ni < 4; ++ni) acc[mi][ni] = zero;

  STAGE(0, 0);
  STAGE(1, 32);
  asm volatile("s_waitcnt vmcnt(3)" ::: "memory");
  __builtin_amdgcn_s_barrier();
  __builtin_amdgcn_sched_barrier(0);

  int cur = 0;
  for (int step = 0; step < 32; ++step) {
    if (step < 30) {
      const int nb = (cur == 0) ? 2 : cur - 1;
      STAGE(nb, step * 32 + 64);
    }
    s8v a[2], b[4];
    for (int mi = 0; mi < 2; ++mi) a[mi] = *(const s8v*)&As[cur][(wm + mi * 16 + ln) * 32 + cfrag];
    for (int ni = 0; ni < 4; ++ni) b[ni] = *(const s8v*)&Bs[cur][(wn + ni * 16 + ln) * 32 + cfrag];
    for (int mi = 0; mi < 2; ++mi)
      for (int ni = 0; ni < 4; ++ni)
        acc[mi][ni] = __builtin_amdgcn_mfma_f32_16x16x32_bf16(a[mi], b[ni], acc[mi][ni], 0, 0, 0);
    if (step < 30)       asm volatile("s_waitcnt vmcnt(3)" ::: "memory");
    else if (step == 30) asm volatile("s_waitcnt vmcnt(0)" ::: "memory");
    if (step < 31) {
      __builtin_amdgcn_s_barrier();
      __builtin_amdgcn_sched_barrier(0);
    }
    cur = (cur == 2) ? 0 : cur + 1;
  }

  for (int mi = 0; mi < 2; ++mi) {
    int rb = m0 + wm + mi * 16 + quad * 4;
    for (int ni = 0; ni < 4; ++ni) {
      int col = n0 + wn + ni * 16 + ln;
      float bvv = bias[col];
      for (int r = 0; r < 4; ++r)
        out[(size_t)(rb + r) * 1024 + col] = acc[mi][ni][r] + bvv;
    }
  }
}

extern "C" void kernel_launch(void* const* d_in, const int* in_sizes, int n_in,
                              void* d_out, int out_size, void* d_ws, size_t ws_size,
                              hipStream_t stream) {
  const float* Q  = (const float*)d_in[0];
  const float* K  = (const float*)d_in[1];
  const float* V  = (const float*)d_in[2];
  const int* mask = (const int*)d_in[3];
  const float* Wq = (const float*)d_in[4];
  const float* bq = (const float*)d_in[5];
  const float* Wk = (const float*)d_in[6];
  const float* bk = (const float*)d_in[7];
  const float* Wv = (const float*)d_in[8];
  const float* bv = (const float*)d_in[9];
  const float* Wo = (const float*)d_in[10];
  const float* bo = (const float*)d_in[11];
  float* out = (float*)d_out;

  char* ws = (char*)d_ws;
  const size_t MB = 1u << 20;
  unsigned short* qb  = (unsigned short*)(ws + 0 * MB);
  unsigned short* kb  = (unsigned short*)(ws + 8 * MB);
  unsigned short* vb  = (unsigned short*)(ws + 16 * MB);
  unsigned short* wqt = (unsigned short*)(ws + 24 * MB);
  unsigned short* wkt = (unsigned short*)(ws + 26 * MB);
  unsigned short* wvt = (unsigned short*)(ws + 28 * MB);
  unsigned short* wot = (unsigned short*)(ws + 30 * MB);
  unsigned short* qh  = (unsigned short*)(ws + 32 * MB);
  unsigned short* kh  = (unsigned short*)(ws + 40 * MB);
  unsigned short* vth = (unsigned short*)(ws + 48 * MB);
  unsigned* bmw       = (unsigned*)(ws + 56 * MB);       // 8 MB of packed mask words
  unsigned short* ctx = (unsigned short*)(ws + 16 * MB);  // aliases vb (dead after proj3)

  prep_kernel<<<21504, 256, 0, stream>>>(Q, K, V, qb, kb, vb,
                                         Wq, Wk, Wv, Wo, wqt, wkt, wvt, wot,
                                         mask, bmw);
  proj3_kernel<<<dim3(32, 8, 3), 256, 0, stream>>>(qb, kb, vb, wqt, wkt, wvt,
                                                   bq, bk, bv, qh, kh, vth);
  flash_kernel<<<dim3(16, 32), 256, 0, stream>>>(qh, kh, vth, bmw, ctx);
  gemm_out_kernel<<<dim3(64, 8), 256, 0, stream>>>(ctx, wot, bo, out);
}